// Round 7
// baseline (198.751 us; speedup 1.0000x reference)
//
#include <hip/hip_runtime.h>
#include <hip/hip_bf16.h>

#define SEQ    576
#define DIM    640
#define HEADS  8
#define HD     80          // DIM / HEADS
#define NF     4
#define NB     12          // 3 * NF
#define M_TOT  (NB * SEQ)  // 6912
#define SCALE  0.11180339887498949f   // 1/sqrt(80)
#define LOG2E  1.4426950408889634f

typedef __attribute__((ext_vector_type(8))) short          bf16x8;
typedef __attribute__((ext_vector_type(4))) float          f32x4;
typedef __attribute__((ext_vector_type(8))) unsigned short u16x8;
typedef __attribute__((ext_vector_type(4))) unsigned short u16x4;

__device__ __forceinline__ unsigned short f2bf(float x) {
    unsigned u = __float_as_uint(x);
    u += 0x7fffu + ((u >> 16) & 1u);
    return (unsigned short)(u >> 16);
}
__device__ __forceinline__ float bf2f(unsigned short h) {
    return __uint_as_float((unsigned)h << 16);
}
__device__ __forceinline__ f32x4 mfma16(bf16x8 a, bf16x8 b, f32x4 c) {
    return __builtin_amdgcn_mfma_f32_16x16x32_bf16(a, b, c, 0, 0, 0);
}
__device__ __forceinline__ float fexp2(float x) {
    return __builtin_amdgcn_exp2f(x);
}
__device__ __forceinline__ float max3f(float a, float b, float c) {
    return fmaxf(fmaxf(a, b), c);   // clang fuses to v_max3_f32
}
// async global->LDS DMA, 16B/lane, dest = lds base + lane*16
__device__ __forceinline__ void dma16(const void* g, void* s) {
    __builtin_amdgcn_global_load_lds(
        (const __attribute__((address_space(1))) void*)g,
        (__attribute__((address_space(3))) void*)s, 16, 0, 0);
}

// ---------------------------------------------------------------------------
// Convert fp32 -> bf16 (single, round-to-nearest). z: 0=X, 1=Wq(*SCALE*LOG2E),
// 2=Wk, 3=Wv, 4=Wo. grid=(1080,5), block 256, 16 elems/thread.
// ---------------------------------------------------------------------------
__global__ __launch_bounds__(256) void split_kernel(
    const float* __restrict__ X,  const float* __restrict__ Wq,
    const float* __restrict__ Wk, const float* __restrict__ Wv,
    const float* __restrict__ Wo,
    unsigned short* __restrict__ Xh,  unsigned short* __restrict__ Wqh,
    unsigned short* __restrict__ Wkh, unsigned short* __restrict__ Wvh,
    unsigned short* __restrict__ Woh)
{
    const int z = blockIdx.y;
    const float* src; unsigned short* dh; int n; float s = 1.0f;
    switch (z) {
        case 0:  src = X;  dh = Xh;  n = M_TOT * DIM; break;
        case 1:  src = Wq; dh = Wqh; n = DIM * DIM; s = SCALE * LOG2E; break;
        case 2:  src = Wk; dh = Wkh; n = DIM * DIM; break;
        case 3:  src = Wv; dh = Wvh; n = DIM * DIM; break;
        default: src = Wo; dh = Woh; n = DIM * DIM; break;
    }
    const int base = blockIdx.x * 4096 + threadIdx.x * 16;
    if (base >= n) return;
#pragma unroll
    for (int half = 0; half < 2; ++half) {
        const int b = base + half * 8;
        float4 a4 = *(const float4*)(src + b);
        float4 b4 = *(const float4*)(src + b + 4);
        float vv[8] = {a4.x, a4.y, a4.z, a4.w, b4.x, b4.y, b4.z, b4.w};
        union { unsigned short u[8]; u16x8 v; } ph;
#pragma unroll
        for (int j = 0; j < 8; ++j) ph.u[j] = f2bf(vv[j] * s);
        *(u16x8*)(dh + b) = ph.v;
    }
}

// ---------------------------------------------------------------------------
// QKV GEMM (single bf16). Tile 256(M) x 64(N), BK=32, block 256.
// Staging via global_load_lds (16B/lane), unpadded [r][32] LDS.
// grid=(27,10,3); z epilogue: 0 -> Qh bf16, 1 -> Kb bf16, 2 -> Vt transpose.
// ROUND-11: bijective XCD swizzle (m204 variant) -> A re-reads are L2 hits.
// ROUND-12: 2-phase double-buffered prefetch (one barrier/iter drain).
// ---------------------------------------------------------------------------
__global__ __launch_bounds__(256) void qkv_mfma_kernel(
    const unsigned short* __restrict__ Xh,
    const unsigned short* __restrict__ Wqh, const unsigned short* __restrict__ Wkh,
    const unsigned short* __restrict__ Wvh,
    unsigned short* __restrict__ Qh,
    unsigned short* __restrict__ Kb, unsigned short* __restrict__ VtG)
{
    __shared__ unsigned short smem[2][10240];   // 40 KB, double-buffered

    // ---- XCD-aware bijective remap: 810 blocks = 8*101 + 2 ----
    const int flat = blockIdx.x + 27 * (blockIdx.y + 10 * blockIdx.z);
    const int xcd  = flat & 7;
    const int slot = flat >> 3;                      // 0..101
    const int l    = (xcd < 2 ? xcd * 102 : 204 + (xcd - 2) * 101) + slot;
    const int m_idx = l / 30;                        // 0..26 (m-major: 30 tiles/panel)
    const int rem   = l - m_idx * 30;
    const int z     = rem / 10;                      // 0..2
    const int n_idx = rem - z * 10;                  // 0..9

    const unsigned short* WH = (z == 0) ? Wqh : ((z == 1) ? Wkh : Wvh);
    const int m0 = m_idx * 256;
    const int n0 = n_idx * 64;

    const int t    = threadIdx.x;
    const int w    = t >> 6;
    const int lane = t & 63;
    const int quad = lane >> 4;
    const int ln   = lane & 15;

    f32x4 acc[4][4];
#pragma unroll
    for (int mi = 0; mi < 4; ++mi)
#pragma unroll
        for (int nt = 0; nt < 4; ++nt)
#pragma unroll
            for (int e = 0; e < 4; ++e) acc[mi][nt][e] = 0.f;

    const int lr = lane >> 2;          // 0..15 (row within 16-row DMA chunk)
    const int lc = (lane & 3) * 8;     // 0,8,16,24 (shorts)

    // stage K-tile k0 into buffer buf (5 x 1KB DMA per wave)
    auto stage = [&](int buf, int k0) {
        unsigned short* As = smem[buf];
        unsigned short* Bs = smem[buf] + 8192;
        const unsigned short* gp = Xh + (size_t)(m0 + w * 64 + lr) * DIM + k0 + lc;
#pragma unroll
        for (int i = 0; i < 4; ++i)
            dma16(gp + (size_t)i * 16 * DIM, &As[(w * 64 + i * 16) * 32]);
        const size_t gb = (size_t)(n0 + w * 16 + lr) * DIM + k0 + lc;
        dma16(WH + gb, &Bs[w * 16 * 32]);
    };

    stage(0, 0);
    __syncthreads();                       // drains vmcnt(0): buf0 ready

    for (int k0 = 0; k0 < DIM; k0 += 32) {
        const int kb = (k0 >> 5) & 1;
        if (k0 + 32 < DIM) stage(kb ^ 1, k0 + 32);   // prefetch next tile

        const unsigned short* As = smem[kb];
        const unsigned short* Bs = smem[kb] + 8192;
        bf16x8 af[4];
#pragma unroll
        for (int mi = 0; mi < 4; ++mi)
            af[mi] = *(const bf16x8*)&As[(w * 64 + mi * 16 + ln) * 32 + quad * 8];
#pragma unroll
        for (int nt = 0; nt < 4; ++nt) {
            bf16x8 bh = *(const bf16x8*)&Bs[(nt * 16 + ln) * 32 + quad * 8];
#pragma unroll
            for (int mi = 0; mi < 4; ++mi)
                acc[mi][nt] = mfma16(af[mi], bh, acc[mi][nt]);
        }
        __syncthreads();   // vmcnt(0): prefetch landed; reads of kb done
    }

    if (z == 0) {
#pragma unroll
        for (int mi = 0; mi < 4; ++mi)
#pragma unroll
            for (int r = 0; r < 4; ++r) {
                const size_t row = m0 + w * 64 + mi * 16 + quad * 4 + r;
#pragma unroll
                for (int nt = 0; nt < 4; ++nt)
                    Qh[row * DIM + n0 + nt * 16 + ln] = f2bf(acc[mi][nt][r]);
            }
    } else if (z == 1) {
#pragma unroll
        for (int mi = 0; mi < 4; ++mi)
#pragma unroll
            for (int r = 0; r < 4; ++r) {
                const size_t row = m0 + w * 64 + mi * 16 + quad * 4 + r;
#pragma unroll
                for (int nt = 0; nt < 4; ++nt)
                    Kb[row * DIM + n0 + nt * 16 + ln] = f2bf(acc[mi][nt][r]);
            }
    } else {
        // transpose 256x64 -> Vt[64 n][256 m] in two 128-col halves via LDS
        unsigned short* Vts = smem[0];   // 64 x 136 = 8704 shorts
#pragma unroll 1
        for (int half = 0; half < 2; ++half) {
            __syncthreads();
            if ((w >> 1) == half) {
                const int wl = w & 1;
#pragma unroll
                for (int mi = 0; mi < 4; ++mi)
#pragma unroll
                    for (int nt = 0; nt < 4; ++nt)
#pragma unroll
                        for (int r = 0; r < 4; ++r)
                            Vts[(nt * 16 + ln) * 136 + wl * 64 + mi * 16 + quad * 4 + r] =
                                f2bf(acc[mi][nt][r]);
            }
            __syncthreads();
            const int nn = t & 63;
            const int c0 = (t >> 6) * 32;
#pragma unroll
            for (int i = 0; i < 4; ++i)
                *(u16x8*)(VtG + (size_t)(n0 + nn) * M_TOT + m0 + half * 128 + c0 + i * 8) =
                    *(const u16x8*)&Vts[nn * 136 + c0 + i * 8];
        }
    }
}

// ---------------------------------------------------------------------------
// Flash attention v13 (round-17). grid=(3,8,28), block 256 (4 waves x 48
// q-rows). Inner loop = round-16 (P never touches LDS via sigma-permuted
// K staging; O^T PV; per-lane rescale/epilogue; defer-max; quad-partial l;
// zero bank conflicts). UNCHANGED this round.
// ROUND-17: re-apply the 3-way cross split (round-14) now that its failure
// cause is fixed: LDS is 45 KB -> 3 blocks/CU -> all 672 blocks co-resident
// (round-14 failed at 72.7 KB: only 512/672 resident + ragged tail), and
// setprio is gone. Occupancy was the round-16 limiter (14.6%: ~1.2 waves/
// SIMD can't overlap QK-MFMA -> softmax-VALU -> PV-MFMA chains).
// Pn = 24 partials fills d_out EXACTLY; ml in dead Wqh/Wkh; 3-way merge.
// NOTE: never leave MFMA-read LDS uninitialized — 0*NaN = NaN (round-7 bug).
// NOTE: 128-thread blocks double FETCH + VGPR (round-9 regression) — keep 256.
// NOTE: no launch_bounds waves-cap / register-retained P across fences
// (round-15 spill).
// z<24: cross partial -> (Pn,ml); z>=24: self frame -> Oh.
// ---------------------------------------------------------------------------
__global__ __launch_bounds__(256, 2) void attn_mfma_kernel(
    const unsigned short* __restrict__ Qh,
    const unsigned short* __restrict__ Kb, const unsigned short* __restrict__ Vt,
    unsigned short* __restrict__ Oh,
    unsigned short* __restrict__ Pn, float2* __restrict__ ml)
{
    // ---- XCD-aware remap: one head per XCD (672 = 8*84, bijective) ----
    const int flat = blockIdx.x + 3 * (blockIdx.y + 8 * blockIdx.z);
    const int h    = flat & 7;          // head = XCD
    const int slot = flat >> 3;         // 0..83
    const int z    = slot / 3;          // 0..27
    const int qt   = slot - z * 3;      // 0..2

    int f, kbase, nkt, idx = -1;
    if (z < 24) {
        idx = z;
        const int fi = z / 3;            // cross frame 0..7
        const int part = z - fi * 3;     // partial 0..2
        f = 4 + fi;
        kbase = (fi < 4 ? 4 : 8) * SEQ + part * 768;
        nkt = 12;
    } else {
        f = z - 24;
        kbase = f * SEQ;
        nkt = 9;
    }

    const int t    = threadIdx.x;
    const int w    = t >> 6;
    const int lane = t & 63;
    const int quad = lane >> 4;
    const int ln   = lane & 15;

    __shared__ unsigned short KhS[2][12 * 64 * 8]; // 24,576 B, sigma-permuted
    __shared__ unsigned short VtS[2][80 * 64];     // 20,480 B, swizzled cols

    // sigma^-1: staging lane -> physical key offset within the 64-key tile
    const int klane = (lane & 3) | (((lane >> 4) & 1) << 2) |
                      (((lane >> 2) & 3) << 3) | (lane & 32);

    // ---- Q fragments (B-operand of S^T) ----
    bf16x8 qf[3][3];
#pragma unroll
    for (int mi = 0; mi < 3; ++mi) {
        const int qrow = f * SEQ + qt * 192 + w * 48 + mi * 16 + ln;
        const unsigned short* qp = Qh + (size_t)qrow * DIM + h * HD;
#pragma unroll
        for (int kc = 0; kc < 3; ++kc) {
            const int dbase = kc * 32 + quad * 8;
            if (dbase < HD) {
                qf[mi][kc] = *(const bf16x8*)(qp + dbase);
            } else {
                union { unsigned short u[8]; bf16x8 v; } zz;
#pragma unroll
                for (int j = 0; j < 8; ++j) zz.u[j] = 0;
                qf[mi][kc] = zz.v;
            }
        }
    }

    // staging helpers -------------------------------------------------------
    auto stage_k = [&](int buf, int kvt) {
        const unsigned short* kg = Kb + (size_t)(kbase + kvt * 64) * DIM + h * HD;
#pragma unroll
        for (int rnd = 0; rnd < 3; ++rnd) {
            const int g = rnd * 4 + w;          // d-colgroup 0..11
            dma16(kg + (size_t)klane * DIM + g * 8, &KhS[buf][g * 512]);
        }
    };
    u16x8 vreg[3];
    auto load_v = [&](int kvt) {
#pragma unroll
        for (int i = 0; i < 3; ++i) {
            const int u = t + i * 256;
            if (u < 640) {
                const int d = u >> 3, c8 = u & 7;
                vreg[i] = *(const u16x8*)(Vt + (size_t)(h * HD + d) * M_TOT +
                                          kbase + kvt * 64 + c8 * 8);
            }
        }
    };
    auto write_v = [&](int buf) {
#pragma unroll
        for (int i = 0; i < 3; ++i) {
            const int u = t + i * 256;
            if (u < 640) {
                const int d = u >> 3, c8 = u & 7;
                const int c8s = (c8 + 3 * d) & 7;
                *(u16x8*)&VtS[buf][d * 64 + c8s * 8] = vreg[i];
            }
        }
    };

    // per-lane softmax state for q = mi*16 + ln (m replicated across quads;
    // l is a QUAD-PARTIAL sum — cross-quad reduced once in epilogue)
    float m_[3], l_[3];
#pragma unroll
    for (int mi = 0; mi < 3; ++mi) { m_[mi] = -INFINITY; l_[mi] = 0.f; }

    // oacc is O^T: lane(ln,quad) reg r holds O[q=mi*16+ln][d=nt*16+quad*4+r]
    f32x4 oacc[3][5];
#pragma unroll
    for (int mi = 0; mi < 3; ++mi)
#pragma unroll
        for (int nt = 0; nt < 5; ++nt)
#pragma unroll
            for (int e = 0; e < 4; ++e) oacc[mi][nt][e] = 0.f;

    // ---- prologue: stage tile 0 into buffer 0 ----
    stage_k(0, 0);
    load_v(0);
    write_v(0);          // compiler waits vmcnt for vreg before ds_write
    __syncthreads();     // vmcnt(0): K-DMA landed; lgkm(0): V writes visible

    for (int kt = 0; kt < nkt; ++kt) {
        const int cur = kt & 1;
        const bool pf = (kt + 1 < nkt);

        // ---- prefetch next tile: issue loads, keep in flight ----
        if (pf) {
            load_v(kt + 1);            // global->reg, vmcnt in flight
            stage_k(cur ^ 1, kt + 1);  // global->LDS DMA, vmcnt in flight
        }

        // ---- S^T = K.Q^T (zero-C first MFMA; sigma-permuted key rows) ----
        const f32x4 fz = {0.f, 0.f, 0.f, 0.f};
        f32x4 sacc[3][4];
#pragma unroll
        for (int nt = 0; nt < 4; ++nt) {
            const int ks = ln + 16 * (nt >> 1) + 32 * (nt & 1);
#pragma unroll
            for (int kc = 0; kc < 3; ++kc) {
                bf16x8 kf = *(const bf16x8*)&KhS[cur][((kc * 4 + quad) * 64 + ks) * 8];
#pragma unroll
                for (int mi = 0; mi < 3; ++mi)
                    sacc[mi][nt] = (kc == 0)
                        ? mfma16(kf, qf[mi][0], fz)
                        : mfma16(kf, qf[mi][kc], sacc[mi][nt]);  // swapped!
            }
        }

        // ---- softmax: max3 trees, defer-max, quad-partial l ----
        float mxl[3];
#pragma unroll
        for (int mi = 0; mi < 3; ++mi) {
            const f32x4* S = sacc[mi];
            const float a = max3f(S[0][0], S[0][1], S[0][2]);
            const float b = max3f(S[0][3], S[1][0], S[1][1]);
            const float c = max3f(S[1][2], S[1][3], S[2][0]);
            const float d = max3f(S[2][1], S[2][2], S[2][3]);
            const float e = max3f(S[3][0], S[3][1], S[3][2]);
            mxl[mi] = fmaxf(max3f(a, b, c), max3f(d, e, S[3][3]));
        }
        const bool need = (mxl[0] > m_[0] + 8.0f) || (mxl[1] > m_[1] + 8.0f) ||
                          (mxl[2] > m_[2] + 8.0f);
        if (__any(need)) {           // wave-uniform slow path (rare)
#pragma unroll
            for (int mi = 0; mi < 3; ++mi) {
                float mx = fmaxf(mxl[mi], __shfl_xor(mxl[mi], 16));
                mx = fmaxf(mx, __shfl_xor(mx, 32));
                const float mnew = fmaxf(m_[mi], mx);
                const float aq = fexp2(m_[mi] - mnew);
                m_[mi] = mnew;
                l_[mi] *= aq;
                // O^T layout: q = ln per-lane -> rescale needs NO shuffles
#pragma unroll
                for (int nt = 0; nt < 5; ++nt)
#pragma unroll
                    for (int e = 0; e < 4; ++e) oacc[mi][nt][e] *= aq;
            }
        }
        // ---- exp + pack straight into PV B-frags (NO LDS round-trip) ----
        bf16x8 pfv[3][2];
#pragma unroll
        for (int mi = 0; mi < 3; ++mi) {
            float s = 0.f;
            float p[4][4];
#pragma unroll
            for (int nt = 0; nt < 4; ++nt) {
#pragma unroll
                for (int r = 0; r < 4; ++r) {
                    p[nt][r] = fexp2(sacc[mi][nt][r] - m_[mi]);
                    s += p[nt][r];
                }
            }
            union { unsigned w[4]; bf16x8 v; } u0, u1;
            u0.w[0] = __builtin_amdgcn_perm(__float_as_uint(p[0][1]),
                                            __float_as_uint(p[0][0]), 0x07060302u);
            u0.w[1] = __builtin_amdgcn_perm(__float_as_uint(p[0][3]),
                                            __float_as_uint(p[0][2]), 0x07060302u);
            u0.w[2] = __builtin_amdgcn_perm(__float_as_uint(p[2][1]),
                                            __float_as_uint(p[2][0]), 0x07060302u);
            u0.w[3] = __builtin_amdgcn_perm(__float_as_uint(p[2][3]),
                                            __float_as_uint(p[2][2]), 0x07060302u);
            u1.w[0] = __builtin_amdgcn_perm(__float_as_uint(p[1][1]),
                                            __float_as_uint(p[1][0]), 0x07060302u);
            u1.w[1] = __builtin_amdgcn_perm(__float_as_uint(p[1][3]),
                                            __float_as_uint(p[1][2]), 0x07060302u);
            u1.w[2] = __builtin_amdgcn_perm(__float_as_uint(p[3][1]),
                                            __float_as_uint(p[3][0]), 0x07060302u);
            u1.w[3] = __builtin_amdgcn_perm(__float_as_uint(p[3][3]),
                                            __float_as_uint(p[3][2]), 0x07060302u);
            pfv[mi][0] = u0.v;
            pfv[mi][1] = u1.v;
            l_[mi] += s;   // quad-partial accumulate (after any aq rescale)
        }

        // ---- O^T += V^T.P : A = V^T from VtS (unchanged reads), B = pfv ----
#pragma unroll
        for (int kc = 0; kc < 2; ++kc)
#pragma unroll
            for (int nt = 0; nt < 5; ++nt) {
                const int vrow = nt * 16 + ln;
                const int c8r  = ((kc * 4 + quad) + 3 * vrow) & 7;
                bf16x8 vf = *(const bf16x8*)&VtS[cur][vrow * 64 + c8r * 8];
#pragma unroll
                for (int mi = 0; mi < 3; ++mi)
                    oacc[mi][nt] = mfma16(vf, pfv[mi][kc], oacc[mi][nt]);
            }

        // ---- land prefetched V into the other buffer, then barrier ----
        if (pf) write_v(cur ^ 1);
        __syncthreads();   // vmcnt(0): next K-DMA landed; all reads of cur done
    }

    // ---- epilogue: cross-quad l reduction; per-lane q=ln, no shuffles ----
#pragma unroll
    for (int mi = 0; mi < 3; ++mi) {
        l_[mi] += __shfl_xor(l_[mi], 16);
        l_[mi] += __shfl_xor(l_[mi], 32);
    }
#pragma unroll
    for (int mi = 0; mi < 3; ++mi) {
        const float inv = 1.f / l_[mi];
        const int rr = qt * 192 + w * 48 + mi * 16 + ln;    // frame-local q-row
#pragma unroll
        for (int nt = 0; nt < 5; ++nt) {
            union { unsigned short u[4]; u16x4 v; } o4;
#pragma unroll
            for (int r = 0; r < 4; ++r) o4.u[r] = f2bf(oacc[mi][nt][r] * inv);
            const int dcol = h * HD + nt * 16 + quad * 4;
            if (idx < 0)
                *(u16x4*)&Oh[((size_t)f * SEQ + rr) * DIM + dcol] = o4.v;
            else
                *(u16x4*)&Pn[((size_t)idx * SEQ + rr) * DIM + dcol] = o4.v;
        }
    }
    if (idx >= 0 && lane < 16) {
#pragma unroll
        for (int mi = 0; mi < 3; ++mi) {
            const int rr = qt * 192 + w * 48 + mi * 16 + lane;
            ml[((size_t)idx * 8 + h) * SEQ + rr] = make_float2(m_[mi], l_[mi]);
        }
    }
}

// ---------------------------------------------------------------------------
// Merge the three partials of each cross frame. grid=(576,8), block 320.
// ---------------------------------------------------------------------------
__global__ __launch_bounds__(320) void merge_kernel(
    const unsigned short* __restrict__ Pn, const float2* __restrict__ ml,
    unsigned short* __restrict__ Oh)
{
    const int row = blockIdx.x;   // 0..575
    const int fi  = blockIdx.y;   // 0..7
    const int t   = threadIdx.x;  // 0..319
    const int i0  = fi * 3, i1 = i0 + 1, i2 = i0 + 2;
#pragma unroll
    for (int rep = 0; rep < 2; ++rep) {
        const int col = t + rep * 320;
        const int h = col / 80;
        const float2 a = ml[((size_t)i0 * 8 + h) * SEQ + row];
        const float2 b = ml[((size_t)i1 * 8 + h) * SEQ + row];
        const float2 c = ml[((size_t)i2 * 8 + h) * SEQ + row];
        const float M  = fmaxf(fmaxf(a.x, b.x), c.x);
        const float w0 = fexp2(a.x - M) * a.y;
        const float w1 = fexp2(b.x - M) * b.y;
        const float w2 = fexp2(c.x - M) * c.y;
        const float inv = 1.f / (w0 + w1 + w2);
        const float p0 = bf2f(Pn[((size_t)i0 * SEQ + row) * DIM + col]);
        const float p1 = bf2f(Pn[((size_t)i1 * SEQ + row) * DIM + col]);
        const float p2 = bf2f(Pn[((size_t)i2 * SEQ + row) * DIM + col]);
        Oh[((size_t)(4 + fi) * SEQ + row) * DIM + col] =
            f2bf((w0 * p0 + w1 * p1 + w2 * p2) * inv);
    }
}

// ---------------------------------------------------------------------------
// Output projection: out = Oh * Wo^T + bo (single bf16), fp32 out.
// Tile 256x64, BK=32, global_load_lds staging. grid=(27,10).
// ROUND-11: bijective XCD swizzle. ROUND-12: 2-phase dbuf prefetch.
// ---------------------------------------------------------------------------
__global__ __launch_bounds__(256) void oproj_mfma_kernel(
    const unsigned short* __restrict__ Oh,
    const unsigned short* __restrict__ Woh,
    const float* __restrict__ bo, float* __restrict__ out)
{
    __shared__ unsigned short smem[2][10240];

    // ---- XCD-aware bijective remap: 270 blocks = 8*33 + 6 ----
    const int flat = blockIdx.x + 27 * blockIdx.y;
    const int xcd  = flat & 7;
    const int slot = flat >> 3;
    const int l    = (xcd < 6 ? xcd * 34 : 204 + (xcd - 6) * 33) + slot;
    const int m_idx = l / 10;                        // m-major
    const int n_idx = l - m_idx * 10;
    const int m0 = m_idx * 256;
    const int n0 = n_idx * 64;

    const int t    = threadIdx.x;
    const int w    = t >> 6;
    const int lane = t & 63;
    const int quad = lane >> 4;
    const int ln   = lane & 15;

    f32x4 acc[4][4];
#pragma unroll
    for (int mi = 0; mi < 4; ++mi)
#pragma unroll
        for (int nt = 0; nt < 4; ++nt)
#pragma unroll
            for (int e = 0; e < 4; ++e) acc[mi][nt][e] = 0.f;

    const int lr = lane >> 2;
    const int lc = (lane & 3) * 8;

    auto stage = [&](int buf, int k0) {
        unsigned short* As = smem[buf];
        unsigned short* Bs = smem[buf] + 8192;
        const unsigned short* gp = Oh + (size_t)(m0 + w * 64 + lr) * DIM + k0 + lc;
#pragma unroll
        for (int i = 0; i < 4; ++i)
            dma16(gp + (size_t)i * 16 * DIM, &As[(w * 64 + i * 16) * 32]);
        const size_t gb = (size_t)(n0 + w * 16 + lr) * DIM + k0 + lc;
        dma16(Woh + gb, &Bs[w * 16 * 32]);
    };

    stage(0, 0);
    __syncthreads();

    for (int k0 = 0; k0 < DIM; k0 += 32) {
        const int kb = (k0 >> 5) & 1;
        if (k0 + 32 < DIM) stage(kb ^ 1, k0 + 32);

        const unsigned short* As = smem[kb];
        const unsigned short* Bs = smem[kb] + 8192;
        bf16x8 af[4];
#pragma unroll
        for (int mi = 0; mi < 4; ++mi)
            af[mi] = *(const bf16x8*)&As[(w * 64 + mi * 16 + ln) * 32 + quad * 8];
#pragma unroll
        for (int nt = 0; nt < 4; ++nt) {
            bf16x8 bh = *(const bf16x8*)&Bs[(nt * 16 + ln) * 32 + quad * 8];
#pragma unroll
            for (int mi = 0; mi < 4; ++mi)
                acc[mi][nt] = mfma16(af[mi], bh, acc[mi][nt]);
        }
        __syncthreads();
    }

#pragma unroll
    for (int mi = 0; mi < 4; ++mi)
#pragma unroll
        for (int r = 0; r < 4; ++r) {
            const size_t row = m0 + w * 64 + mi * 16 + quad * 4 + r;
#pragma unroll
            for (int nt = 0; nt < 4; ++nt) {
                const int col = n0 + nt * 16 + ln;
                out[row * DIM + col] = acc[mi][nt][r] + bo[col];
            }
        }
}

// ---------------------------------------------------------------------------
extern "C" void kernel_launch(void* const* d_in, const int* in_sizes, int n_in,
                              void* d_out, int out_size, void* d_ws, size_t ws_size,
                              hipStream_t stream)
{
    const float* x  = (const float*)d_in[0];
    const float* Wq = (const float*)d_in[1];
    const float* Wk = (const float*)d_in[2];
    const float* Wv = (const float*)d_in[3];
    const float* Wo = (const float*)d_in[4];
    const float* bo = (const float*)d_in[5];
    float* out = (float*)d_out;

    const size_t NX = (size_t)M_TOT * DIM;   // 4,423,680
    const size_t NW = (size_t)DIM * DIM;     // 409,600
    unsigned short* p = (unsigned short*)d_ws;
    unsigned short* Wqh = p;  p += NW;
    unsigned short* Wkh = p;  p += NW;
    unsigned short* Wvh = p;  p += NW;
    unsigned short* Woh = p;  p += NW;
    unsigned short* Xh  = p;  p += NX;
    unsigned short* Qhb = p;  p += NX;
    unsigned short* Kbb = p;  p += NX;
    unsigned short* Vtb = p;  p += NX;
    unsigned short* Ohb = Xh;                 // Xh dead after QKV GEMM

    // flash-decoding partials: Pn (24 partials) fills d_out EXACTLY
    // (24*576*640*2 B == 6912*640*4 B); ml lives in the dead Wqh/Wkh region
    // (written by attn AFTER qkv read the weights; read by merge BEFORE oproj).
    unsigned short* Pn = (unsigned short*)d_out;
    float2* ml = (float2*)Wqh;                // 884 KB < 1.64 MB (Wqh+Wkh)

    dim3 g0((unsigned)((NX + 4095) / 4096), 5);
    split_kernel<<<g0, 256, 0, stream>>>(x, Wq, Wk, Wv, Wo,
        Xh, Wqh, Wkh, Wvh, Woh);

    dim3 g1(M_TOT / 256, DIM / 64, 3);
    qkv_mfma_kernel<<<g1, 256, 0, stream>>>(Xh, Wqh, Wkh, Wvh, Qhb, Kbb, Vtb);

    dim3 g2(3, HEADS, 28);
    attn_mfma_kernel<<<g2, 256, 0, stream>>>(Qhb, Kbb, Vtb, Ohb, Pn, ml);

    dim3 g3(SEQ, 8);
    merge_kernel<<<g3, 320, 0, stream>>>(Pn, ml, Ohb);

    dim3 g4(M_TOT / 256, DIM / 64);
    oproj_mfma_kernel<<<g4, 256, 0, stream>>>(Ohb, Woh, bo, out);
}

// Round 8
// 186.714 us; speedup vs baseline: 1.0645x; 1.0645x over previous
//
#include <hip/hip_runtime.h>
#include <hip/hip_bf16.h>

#define SEQ    576
#define DIM    640
#define HEADS  8
#define HD     80          // DIM / HEADS
#define NF     4
#define NB     12          // 3 * NF
#define M_TOT  (NB * SEQ)  // 6912
#define SCALE  0.11180339887498949f   // 1/sqrt(80)
#define LOG2E  1.4426950408889634f

typedef __attribute__((ext_vector_type(8))) short          bf16x8;
typedef __attribute__((ext_vector_type(4))) float          f32x4;
typedef __attribute__((ext_vector_type(8))) unsigned short u16x8;
typedef __attribute__((ext_vector_type(4))) unsigned short u16x4;

__device__ __forceinline__ unsigned short f2bf(float x) {
    unsigned u = __float_as_uint(x);
    u += 0x7fffu + ((u >> 16) & 1u);
    return (unsigned short)(u >> 16);
}
__device__ __forceinline__ float bf2f(unsigned short h) {
    return __uint_as_float((unsigned)h << 16);
}
__device__ __forceinline__ f32x4 mfma16(bf16x8 a, bf16x8 b, f32x4 c) {
    return __builtin_amdgcn_mfma_f32_16x16x32_bf16(a, b, c, 0, 0, 0);
}
__device__ __forceinline__ float fexp2(float x) {
    return __builtin_amdgcn_exp2f(x);
}
__device__ __forceinline__ float max3f(float a, float b, float c) {
    return fmaxf(fmaxf(a, b), c);   // clang fuses to v_max3_f32
}
// async global->LDS DMA, 16B/lane, dest = lds base + lane*16
__device__ __forceinline__ void dma16(const void* g, void* s) {
    __builtin_amdgcn_global_load_lds(
        (const __attribute__((address_space(1))) void*)g,
        (__attribute__((address_space(3))) void*)s, 16, 0, 0);
}

// ---------------------------------------------------------------------------
// Convert fp32 -> bf16 (single, round-to-nearest). z: 0=X, 1=Wq(*SCALE*LOG2E),
// 2=Wk, 3=Wv, 4=Wo. grid=(1080,5), block 256, 16 elems/thread.
// ---------------------------------------------------------------------------
__global__ __launch_bounds__(256) void split_kernel(
    const float* __restrict__ X,  const float* __restrict__ Wq,
    const float* __restrict__ Wk, const float* __restrict__ Wv,
    const float* __restrict__ Wo,
    unsigned short* __restrict__ Xh,  unsigned short* __restrict__ Wqh,
    unsigned short* __restrict__ Wkh, unsigned short* __restrict__ Wvh,
    unsigned short* __restrict__ Woh)
{
    const int z = blockIdx.y;
    const float* src; unsigned short* dh; int n; float s = 1.0f;
    switch (z) {
        case 0:  src = X;  dh = Xh;  n = M_TOT * DIM; break;
        case 1:  src = Wq; dh = Wqh; n = DIM * DIM; s = SCALE * LOG2E; break;
        case 2:  src = Wk; dh = Wkh; n = DIM * DIM; break;
        case 3:  src = Wv; dh = Wvh; n = DIM * DIM; break;
        default: src = Wo; dh = Woh; n = DIM * DIM; break;
    }
    const int base = blockIdx.x * 4096 + threadIdx.x * 16;
    if (base >= n) return;
#pragma unroll
    for (int half = 0; half < 2; ++half) {
        const int b = base + half * 8;
        float4 a4 = *(const float4*)(src + b);
        float4 b4 = *(const float4*)(src + b + 4);
        float vv[8] = {a4.x, a4.y, a4.z, a4.w, b4.x, b4.y, b4.z, b4.w};
        union { unsigned short u[8]; u16x8 v; } ph;
#pragma unroll
        for (int j = 0; j < 8; ++j) ph.u[j] = f2bf(vv[j] * s);
        *(u16x8*)(dh + b) = ph.v;
    }
}

// ---------------------------------------------------------------------------
// QKV GEMM (single bf16). Tile 256(M) x 64(N), BK=32, block 256.
// Staging via global_load_lds (16B/lane), unpadded [r][32] LDS.
// grid=(27,10,3); z epilogue: 0 -> Qh bf16, 1 -> Kb bf16, 2 -> Vt transpose.
// ROUND-11: bijective XCD swizzle (m204 variant) -> A re-reads are L2 hits.
// ROUND-12: 2-phase double-buffered prefetch (one barrier/iter drain).
// ---------------------------------------------------------------------------
__global__ __launch_bounds__(256) void qkv_mfma_kernel(
    const unsigned short* __restrict__ Xh,
    const unsigned short* __restrict__ Wqh, const unsigned short* __restrict__ Wkh,
    const unsigned short* __restrict__ Wvh,
    unsigned short* __restrict__ Qh,
    unsigned short* __restrict__ Kb, unsigned short* __restrict__ VtG)
{
    __shared__ unsigned short smem[2][10240];   // 40 KB, double-buffered

    // ---- XCD-aware bijective remap: 810 blocks = 8*101 + 2 ----
    const int flat = blockIdx.x + 27 * (blockIdx.y + 10 * blockIdx.z);
    const int xcd  = flat & 7;
    const int slot = flat >> 3;                      // 0..101
    const int l    = (xcd < 2 ? xcd * 102 : 204 + (xcd - 2) * 101) + slot;
    const int m_idx = l / 30;                        // 0..26 (m-major: 30 tiles/panel)
    const int rem   = l - m_idx * 30;
    const int z     = rem / 10;                      // 0..2
    const int n_idx = rem - z * 10;                  // 0..9

    const unsigned short* WH = (z == 0) ? Wqh : ((z == 1) ? Wkh : Wvh);
    const int m0 = m_idx * 256;
    const int n0 = n_idx * 64;

    const int t    = threadIdx.x;
    const int w    = t >> 6;
    const int lane = t & 63;
    const int quad = lane >> 4;
    const int ln   = lane & 15;

    f32x4 acc[4][4];
#pragma unroll
    for (int mi = 0; mi < 4; ++mi)
#pragma unroll
        for (int nt = 0; nt < 4; ++nt)
#pragma unroll
            for (int e = 0; e < 4; ++e) acc[mi][nt][e] = 0.f;

    const int lr = lane >> 2;          // 0..15 (row within 16-row DMA chunk)
    const int lc = (lane & 3) * 8;     // 0,8,16,24 (shorts)

    // stage K-tile k0 into buffer buf (5 x 1KB DMA per wave)
    auto stage = [&](int buf, int k0) {
        unsigned short* As = smem[buf];
        unsigned short* Bs = smem[buf] + 8192;
        const unsigned short* gp = Xh + (size_t)(m0 + w * 64 + lr) * DIM + k0 + lc;
#pragma unroll
        for (int i = 0; i < 4; ++i)
            dma16(gp + (size_t)i * 16 * DIM, &As[(w * 64 + i * 16) * 32]);
        const size_t gb = (size_t)(n0 + w * 16 + lr) * DIM + k0 + lc;
        dma16(WH + gb, &Bs[w * 16 * 32]);
    };

    stage(0, 0);
    __syncthreads();                       // drains vmcnt(0): buf0 ready

    for (int k0 = 0; k0 < DIM; k0 += 32) {
        const int kb = (k0 >> 5) & 1;
        if (k0 + 32 < DIM) stage(kb ^ 1, k0 + 32);   // prefetch next tile

        const unsigned short* As = smem[kb];
        const unsigned short* Bs = smem[kb] + 8192;
        bf16x8 af[4];
#pragma unroll
        for (int mi = 0; mi < 4; ++mi)
            af[mi] = *(const bf16x8*)&As[(w * 64 + mi * 16 + ln) * 32 + quad * 8];
#pragma unroll
        for (int nt = 0; nt < 4; ++nt) {
            bf16x8 bh = *(const bf16x8*)&Bs[(nt * 16 + ln) * 32 + quad * 8];
#pragma unroll
            for (int mi = 0; mi < 4; ++mi)
                acc[mi][nt] = mfma16(af[mi], bh, acc[mi][nt]);
        }
        __syncthreads();   // vmcnt(0): prefetch landed; reads of kb done
    }

    if (z == 0) {
#pragma unroll
        for (int mi = 0; mi < 4; ++mi)
#pragma unroll
            for (int r = 0; r < 4; ++r) {
                const size_t row = m0 + w * 64 + mi * 16 + quad * 4 + r;
#pragma unroll
                for (int nt = 0; nt < 4; ++nt)
                    Qh[row * DIM + n0 + nt * 16 + ln] = f2bf(acc[mi][nt][r]);
            }
    } else if (z == 1) {
#pragma unroll
        for (int mi = 0; mi < 4; ++mi)
#pragma unroll
            for (int r = 0; r < 4; ++r) {
                const size_t row = m0 + w * 64 + mi * 16 + quad * 4 + r;
#pragma unroll
                for (int nt = 0; nt < 4; ++nt)
                    Kb[row * DIM + n0 + nt * 16 + ln] = f2bf(acc[mi][nt][r]);
            }
    } else {
        // transpose 256x64 -> Vt[64 n][256 m] in two 128-col halves via LDS
        unsigned short* Vts = smem[0];   // 64 x 136 = 8704 shorts
#pragma unroll 1
        for (int half = 0; half < 2; ++half) {
            __syncthreads();
            if ((w >> 1) == half) {
                const int wl = w & 1;
#pragma unroll
                for (int mi = 0; mi < 4; ++mi)
#pragma unroll
                    for (int nt = 0; nt < 4; ++nt)
#pragma unroll
                        for (int r = 0; r < 4; ++r)
                            Vts[(nt * 16 + ln) * 136 + wl * 64 + mi * 16 + quad * 4 + r] =
                                f2bf(acc[mi][nt][r]);
            }
            __syncthreads();
            const int nn = t & 63;
            const int c0 = (t >> 6) * 32;
#pragma unroll
            for (int i = 0; i < 4; ++i)
                *(u16x8*)(VtG + (size_t)(n0 + nn) * M_TOT + m0 + half * 128 + c0 + i * 8) =
                    *(const u16x8*)&Vts[nn * 136 + c0 + i * 8];
        }
    }
}

// ---------------------------------------------------------------------------
// Flash attention v14 (round-18) = round-16 revert + prologue DMA-first.
// grid=(3,8,20), block 256 (4 waves x 48 q-rows). 2x18 cross split (the
// 3-way split regressed twice: per-block overhead P ~ 10.6 tile-times
// dominates; finer splits multiply P and partial traffic with no makespan
// gain — do NOT retry).
// Inner loop: P never touches LDS (sigma-permuted K staging; lane's 16 S
// values ARE the PV B-frags); O^T PV (per-lane rescale/epilogue); defer-max;
// quad-partial l; zero bank conflicts; K dbuf via DMA; V dbuf via reg-stage.
// ROUND-18: prologue issues K-DMA + V global loads BEFORE the 9 dependent
// Q-frag loads, overlapping tile-0 staging latency with Q-load latency
// (P was measured ~37% of a cross block).
// NOTE: never leave MFMA-read LDS uninitialized — 0*NaN = NaN (round-7 bug).
// NOTE: 128-thread blocks double FETCH + VGPR (round-9 regression).
// NOTE: no launch_bounds waves-cap / register-retained P across fences
// (round-15 spill).
// z<16: cross chunk -> partials (Pn,ml); z>=16: self frame -> Oh (self
// blocks occupy the tail flat-ids = backfill-friendly).
// ---------------------------------------------------------------------------
__global__ __launch_bounds__(256, 2) void attn_mfma_kernel(
    const unsigned short* __restrict__ Qh,
    const unsigned short* __restrict__ Kb, const unsigned short* __restrict__ Vt,
    unsigned short* __restrict__ Oh,
    unsigned short* __restrict__ Pn, float2* __restrict__ ml)
{
    // ---- XCD-aware remap: one head per XCD (480 = 8*60, bijective) ----
    const int flat = blockIdx.x + 3 * (blockIdx.y + 8 * blockIdx.z);
    const int h    = flat & 7;          // head = XCD
    const int slot = flat >> 3;         // 0..59
    const int z    = slot / 3;          // 0..19
    const int qt   = slot - z * 3;      // 0..2

    int f, kbase, nkt, idx = -1;
    if (z < 16) {
        idx = z;
        const int fi = z >> 1;
        f = 4 + fi;
        kbase = ((fi < 4 ? 4 : 8) + (z & 1) * 2) * SEQ;
        nkt = 18;
    } else {
        f = z - 16;
        kbase = f * SEQ;
        nkt = 9;
    }

    const int t    = threadIdx.x;
    const int w    = t >> 6;
    const int lane = t & 63;
    const int quad = lane >> 4;
    const int ln   = lane & 15;

    __shared__ unsigned short KhS[2][12 * 64 * 8]; // 24,576 B, sigma-permuted
    __shared__ unsigned short VtS[2][80 * 64];     // 20,480 B, swizzled cols

    // sigma^-1: staging lane -> physical key offset within the 64-key tile
    const int klane = (lane & 3) | (((lane >> 4) & 1) << 2) |
                      (((lane >> 2) & 3) << 3) | (lane & 32);

    // staging helpers -------------------------------------------------------
    auto stage_k = [&](int buf, int kvt) {
        const unsigned short* kg = Kb + (size_t)(kbase + kvt * 64) * DIM + h * HD;
#pragma unroll
        for (int rnd = 0; rnd < 3; ++rnd) {
            const int g = rnd * 4 + w;          // d-colgroup 0..11
            dma16(kg + (size_t)klane * DIM + g * 8, &KhS[buf][g * 512]);
        }
    };
    u16x8 vreg[3];
    auto load_v = [&](int kvt) {
#pragma unroll
        for (int i = 0; i < 3; ++i) {
            const int u = t + i * 256;
            if (u < 640) {
                const int d = u >> 3, c8 = u & 7;
                vreg[i] = *(const u16x8*)(Vt + (size_t)(h * HD + d) * M_TOT +
                                          kbase + kvt * 64 + c8 * 8);
            }
        }
    };
    auto write_v = [&](int buf) {
#pragma unroll
        for (int i = 0; i < 3; ++i) {
            const int u = t + i * 256;
            if (u < 640) {
                const int d = u >> 3, c8 = u & 7;
                const int c8s = (c8 + 3 * d) & 7;
                *(u16x8*)&VtS[buf][d * 64 + c8s * 8] = vreg[i];
            }
        }
    };

    // ---- prologue part 1: issue tile-0 staging FIRST (latency in flight) ----
    stage_k(0, 0);
    load_v(0);

    // ---- Q fragments (B-operand of S^T) — overlap with staging latency ----
    bf16x8 qf[3][3];
#pragma unroll
    for (int mi = 0; mi < 3; ++mi) {
        const int qrow = f * SEQ + qt * 192 + w * 48 + mi * 16 + ln;
        const unsigned short* qp = Qh + (size_t)qrow * DIM + h * HD;
#pragma unroll
        for (int kc = 0; kc < 3; ++kc) {
            const int dbase = kc * 32 + quad * 8;
            if (dbase < HD) {
                qf[mi][kc] = *(const bf16x8*)(qp + dbase);
            } else {
                union { unsigned short u[8]; bf16x8 v; } zz;
#pragma unroll
                for (int j = 0; j < 8; ++j) zz.u[j] = 0;
                qf[mi][kc] = zz.v;
            }
        }
    }

    // per-lane softmax state for q = mi*16 + ln (m replicated across quads;
    // l is a QUAD-PARTIAL sum — cross-quad reduced once in epilogue)
    float m_[3], l_[3];
#pragma unroll
    for (int mi = 0; mi < 3; ++mi) { m_[mi] = -INFINITY; l_[mi] = 0.f; }

    // oacc is O^T: lane(ln,quad) reg r holds O[q=mi*16+ln][d=nt*16+quad*4+r]
    f32x4 oacc[3][5];
#pragma unroll
    for (int mi = 0; mi < 3; ++mi)
#pragma unroll
        for (int nt = 0; nt < 5; ++nt)
#pragma unroll
            for (int e = 0; e < 4; ++e) oacc[mi][nt][e] = 0.f;

    // ---- prologue part 2: land V, then barrier ----
    write_v(0);          // compiler waits vmcnt for vreg before ds_write
    __syncthreads();     // vmcnt(0): K-DMA landed; lgkm(0): V writes visible

    for (int kt = 0; kt < nkt; ++kt) {
        const int cur = kt & 1;
        const bool pf = (kt + 1 < nkt);

        // ---- prefetch next tile: issue loads, keep in flight ----
        if (pf) {
            load_v(kt + 1);            // global->reg, vmcnt in flight
            stage_k(cur ^ 1, kt + 1);  // global->LDS DMA, vmcnt in flight
        }

        // ---- S^T = K.Q^T (zero-C first MFMA; sigma-permuted key rows) ----
        const f32x4 fz = {0.f, 0.f, 0.f, 0.f};
        f32x4 sacc[3][4];
#pragma unroll
        for (int nt = 0; nt < 4; ++nt) {
            const int ks = ln + 16 * (nt >> 1) + 32 * (nt & 1);
#pragma unroll
            for (int kc = 0; kc < 3; ++kc) {
                bf16x8 kf = *(const bf16x8*)&KhS[cur][((kc * 4 + quad) * 64 + ks) * 8];
#pragma unroll
                for (int mi = 0; mi < 3; ++mi)
                    sacc[mi][nt] = (kc == 0)
                        ? mfma16(kf, qf[mi][0], fz)
                        : mfma16(kf, qf[mi][kc], sacc[mi][nt]);  // swapped!
            }
        }

        // ---- softmax: max3 trees, defer-max, quad-partial l ----
        float mxl[3];
#pragma unroll
        for (int mi = 0; mi < 3; ++mi) {
            const f32x4* S = sacc[mi];
            const float a = max3f(S[0][0], S[0][1], S[0][2]);
            const float b = max3f(S[0][3], S[1][0], S[1][1]);
            const float c = max3f(S[1][2], S[1][3], S[2][0]);
            const float d = max3f(S[2][1], S[2][2], S[2][3]);
            const float e = max3f(S[3][0], S[3][1], S[3][2]);
            mxl[mi] = fmaxf(max3f(a, b, c), max3f(d, e, S[3][3]));
        }
        const bool need = (mxl[0] > m_[0] + 8.0f) || (mxl[1] > m_[1] + 8.0f) ||
                          (mxl[2] > m_[2] + 8.0f);
        if (__any(need)) {           // wave-uniform slow path (rare)
#pragma unroll
            for (int mi = 0; mi < 3; ++mi) {
                float mx = fmaxf(mxl[mi], __shfl_xor(mxl[mi], 16));
                mx = fmaxf(mx, __shfl_xor(mx, 32));
                const float mnew = fmaxf(m_[mi], mx);
                const float aq = fexp2(m_[mi] - mnew);
                m_[mi] = mnew;
                l_[mi] *= aq;
                // O^T layout: q = ln per-lane -> rescale needs NO shuffles
#pragma unroll
                for (int nt = 0; nt < 5; ++nt)
#pragma unroll
                    for (int e = 0; e < 4; ++e) oacc[mi][nt][e] *= aq;
            }
        }
        // ---- exp + pack straight into PV B-frags (NO LDS round-trip) ----
        bf16x8 pfv[3][2];
#pragma unroll
        for (int mi = 0; mi < 3; ++mi) {
            float s = 0.f;
            float p[4][4];
#pragma unroll
            for (int nt = 0; nt < 4; ++nt) {
#pragma unroll
                for (int r = 0; r < 4; ++r) {
                    p[nt][r] = fexp2(sacc[mi][nt][r] - m_[mi]);
                    s += p[nt][r];
                }
            }
            union { unsigned w[4]; bf16x8 v; } u0, u1;
            u0.w[0] = __builtin_amdgcn_perm(__float_as_uint(p[0][1]),
                                            __float_as_uint(p[0][0]), 0x07060302u);
            u0.w[1] = __builtin_amdgcn_perm(__float_as_uint(p[0][3]),
                                            __float_as_uint(p[0][2]), 0x07060302u);
            u0.w[2] = __builtin_amdgcn_perm(__float_as_uint(p[2][1]),
                                            __float_as_uint(p[2][0]), 0x07060302u);
            u0.w[3] = __builtin_amdgcn_perm(__float_as_uint(p[2][3]),
                                            __float_as_uint(p[2][2]), 0x07060302u);
            u1.w[0] = __builtin_amdgcn_perm(__float_as_uint(p[1][1]),
                                            __float_as_uint(p[1][0]), 0x07060302u);
            u1.w[1] = __builtin_amdgcn_perm(__float_as_uint(p[1][3]),
                                            __float_as_uint(p[1][2]), 0x07060302u);
            u1.w[2] = __builtin_amdgcn_perm(__float_as_uint(p[3][1]),
                                            __float_as_uint(p[3][0]), 0x07060302u);
            u1.w[3] = __builtin_amdgcn_perm(__float_as_uint(p[3][3]),
                                            __float_as_uint(p[3][2]), 0x07060302u);
            pfv[mi][0] = u0.v;
            pfv[mi][1] = u1.v;
            l_[mi] += s;   // quad-partial accumulate (after any aq rescale)
        }

        // ---- O^T += V^T.P : A = V^T from VtS (unchanged reads), B = pfv ----
#pragma unroll
        for (int kc = 0; kc < 2; ++kc)
#pragma unroll
            for (int nt = 0; nt < 5; ++nt) {
                const int vrow = nt * 16 + ln;
                const int c8r  = ((kc * 4 + quad) + 3 * vrow) & 7;
                bf16x8 vf = *(const bf16x8*)&VtS[cur][vrow * 64 + c8r * 8];
#pragma unroll
                for (int mi = 0; mi < 3; ++mi)
                    oacc[mi][nt] = mfma16(vf, pfv[mi][kc], oacc[mi][nt]);
            }

        // ---- land prefetched V into the other buffer, then barrier ----
        if (pf) write_v(cur ^ 1);
        __syncthreads();   // vmcnt(0): next K-DMA landed; all reads of cur done
    }

    // ---- epilogue: cross-quad l reduction; per-lane q=ln, no shuffles ----
#pragma unroll
    for (int mi = 0; mi < 3; ++mi) {
        l_[mi] += __shfl_xor(l_[mi], 16);
        l_[mi] += __shfl_xor(l_[mi], 32);
    }
#pragma unroll
    for (int mi = 0; mi < 3; ++mi) {
        const float inv = 1.f / l_[mi];
        const int rr = qt * 192 + w * 48 + mi * 16 + ln;    // frame-local q-row
#pragma unroll
        for (int nt = 0; nt < 5; ++nt) {
            union { unsigned short u[4]; u16x4 v; } o4;
#pragma unroll
            for (int r = 0; r < 4; ++r) o4.u[r] = f2bf(oacc[mi][nt][r] * inv);
            const int dcol = h * HD + nt * 16 + quad * 4;
            if (idx < 0)
                *(u16x4*)&Oh[((size_t)f * SEQ + rr) * DIM + dcol] = o4.v;
            else
                *(u16x4*)&Pn[((size_t)idx * SEQ + rr) * DIM + dcol] = o4.v;
        }
    }
    if (idx >= 0 && lane < 16) {
#pragma unroll
        for (int mi = 0; mi < 3; ++mi) {
            const int rr = qt * 192 + w * 48 + mi * 16 + lane;
            ml[((size_t)idx * 8 + h) * SEQ + rr] = make_float2(m_[mi], l_[mi]);
        }
    }
}

// ---------------------------------------------------------------------------
// Merge the two partials of each cross frame. grid=(576,8), block 320.
// ---------------------------------------------------------------------------
__global__ __launch_bounds__(320) void merge_kernel(
    const unsigned short* __restrict__ Pn, const float2* __restrict__ ml,
    unsigned short* __restrict__ Oh)
{
    const int row = blockIdx.x;   // 0..575
    const int fi  = blockIdx.y;   // 0..7
    const int t   = threadIdx.x;  // 0..319
    const int i0  = fi * 2, i1 = i0 + 1;
#pragma unroll
    for (int rep = 0; rep < 2; ++rep) {
        const int col = t + rep * 320;
        const int h = col / 80;
        const float2 a = ml[((size_t)i0 * 8 + h) * SEQ + row];
        const float2 b = ml[((size_t)i1 * 8 + h) * SEQ + row];
        const float M  = fmaxf(a.x, b.x);
        const float w0 = fexp2(a.x - M) * a.y;
        const float w1 = fexp2(b.x - M) * b.y;
        const float inv = 1.f / (w0 + w1);
        const float p0 = bf2f(Pn[((size_t)i0 * SEQ + row) * DIM + col]);
        const float p1 = bf2f(Pn[((size_t)i1 * SEQ + row) * DIM + col]);
        Oh[((size_t)(4 + fi) * SEQ + row) * DIM + col] = f2bf((w0 * p0 + w1 * p1) * inv);
    }
}

// ---------------------------------------------------------------------------
// Output projection: out = Oh * Wo^T + bo (single bf16), fp32 out.
// Tile 256x64, BK=32, global_load_lds staging. grid=(27,10).
// ROUND-11: bijective XCD swizzle. ROUND-12: 2-phase dbuf prefetch.
// ---------------------------------------------------------------------------
__global__ __launch_bounds__(256) void oproj_mfma_kernel(
    const unsigned short* __restrict__ Oh,
    const unsigned short* __restrict__ Woh,
    const float* __restrict__ bo, float* __restrict__ out)
{
    __shared__ unsigned short smem[2][10240];

    // ---- XCD-aware bijective remap: 270 blocks = 8*33 + 6 ----
    const int flat = blockIdx.x + 27 * blockIdx.y;
    const int xcd  = flat & 7;
    const int slot = flat >> 3;
    const int l    = (xcd < 6 ? xcd * 34 : 204 + (xcd - 6) * 33) + slot;
    const int m_idx = l / 10;                        // m-major
    const int n_idx = l - m_idx * 10;
    const int m0 = m_idx * 256;
    const int n0 = n_idx * 64;

    const int t    = threadIdx.x;
    const int w    = t >> 6;
    const int lane = t & 63;
    const int quad = lane >> 4;
    const int ln   = lane & 15;

    f32x4 acc[4][4];
#pragma unroll
    for (int mi = 0; mi < 4; ++mi)
#pragma unroll
        for (int nt = 0; nt < 4; ++nt)
#pragma unroll
            for (int e = 0; e < 4; ++e) acc[mi][nt][e] = 0.f;

    const int lr = lane >> 2;
    const int lc = (lane & 3) * 8;

    auto stage = [&](int buf, int k0) {
        unsigned short* As = smem[buf];
        unsigned short* Bs = smem[buf] + 8192;
        const unsigned short* gp = Oh + (size_t)(m0 + w * 64 + lr) * DIM + k0 + lc;
#pragma unroll
        for (int i = 0; i < 4; ++i)
            dma16(gp + (size_t)i * 16 * DIM, &As[(w * 64 + i * 16) * 32]);
        const size_t gb = (size_t)(n0 + w * 16 + lr) * DIM + k0 + lc;
        dma16(Woh + gb, &Bs[w * 16 * 32]);
    };

    stage(0, 0);
    __syncthreads();

    for (int k0 = 0; k0 < DIM; k0 += 32) {
        const int kb = (k0 >> 5) & 1;
        if (k0 + 32 < DIM) stage(kb ^ 1, k0 + 32);

        const unsigned short* As = smem[kb];
        const unsigned short* Bs = smem[kb] + 8192;
        bf16x8 af[4];
#pragma unroll
        for (int mi = 0; mi < 4; ++mi)
            af[mi] = *(const bf16x8*)&As[(w * 64 + mi * 16 + ln) * 32 + quad * 8];
#pragma unroll
        for (int nt = 0; nt < 4; ++nt) {
            bf16x8 bh = *(const bf16x8*)&Bs[(nt * 16 + ln) * 32 + quad * 8];
#pragma unroll
            for (int mi = 0; mi < 4; ++mi)
                acc[mi][nt] = mfma16(af[mi], bh, acc[mi][nt]);
        }
        __syncthreads();
    }

#pragma unroll
    for (int mi = 0; mi < 4; ++mi)
#pragma unroll
        for (int r = 0; r < 4; ++r) {
            const size_t row = m0 + w * 64 + mi * 16 + quad * 4 + r;
#pragma unroll
            for (int nt = 0; nt < 4; ++nt) {
                const int col = n0 + nt * 16 + ln;
                out[row * DIM + col] = acc[mi][nt][r] + bo[col];
            }
        }
}

// ---------------------------------------------------------------------------
extern "C" void kernel_launch(void* const* d_in, const int* in_sizes, int n_in,
                              void* d_out, int out_size, void* d_ws, size_t ws_size,
                              hipStream_t stream)
{
    const float* x  = (const float*)d_in[0];
    const float* Wq = (const float*)d_in[1];
    const float* Wk = (const float*)d_in[2];
    const float* Wv = (const float*)d_in[3];
    const float* Wo = (const float*)d_in[4];
    const float* bo = (const float*)d_in[5];
    float* out = (float*)d_out;

    const size_t NX = (size_t)M_TOT * DIM;   // 4,423,680
    const size_t NW = (size_t)DIM * DIM;     // 409,600
    unsigned short* p = (unsigned short*)d_ws;
    unsigned short* Wqh = p;  p += NW;
    unsigned short* Wkh = p;  p += NW;
    unsigned short* Wvh = p;  p += NW;
    unsigned short* Woh = p;  p += NW;
    unsigned short* Xh  = p;  p += NX;
    unsigned short* Qhb = p;  p += NX;
    unsigned short* Kbb = p;  p += NX;
    unsigned short* Vtb = p;  p += NX;
    unsigned short* Ohb = Xh;                 // Xh dead after QKV GEMM

    // flash-decoding partials live in d_out (dead until oproj rewrites it)
    unsigned short* Pn = (unsigned short*)d_out;            // 16*576*640 bf16
    float2* ml = (float2*)((char*)d_out + (size_t)16 * SEQ * DIM * 2);

    dim3 g0((unsigned)((NX + 4095) / 4096), 5);
    split_kernel<<<g0, 256, 0, stream>>>(x, Wq, Wk, Wv, Wo,
        Xh, Wqh, Wkh, Wvh, Woh);

    dim3 g1(M_TOT / 256, DIM / 64, 3);
    qkv_mfma_kernel<<<g1, 256, 0, stream>>>(Xh, Wqh, Wkh, Wvh, Qhb, Kbb, Vtb);

    dim3 g2(3, HEADS, 20);
    attn_mfma_kernel<<<g2, 256, 0, stream>>>(Qhb, Kbb, Vtb, Ohb, Pn, ml);

    dim3 g3(SEQ, 8);
    merge_kernel<<<g3, 320, 0, stream>>>(Pn, ml, Ohb);

    dim3 g4(M_TOT / 256, DIM / 64);
    oproj_mfma_kernel<<<g4, 256, 0, stream>>>(Ohb, Woh, bo, out);
}

// Round 9
// 185.723 us; speedup vs baseline: 1.0701x; 1.0053x over previous
//
#include <hip/hip_runtime.h>
#include <hip/hip_bf16.h>

#define SEQ    576
#define DIM    640
#define HEADS  8
#define HD     80          // DIM / HEADS
#define NF     4
#define NB     12          // 3 * NF
#define M_TOT  (NB * SEQ)  // 6912
#define SCALE  0.11180339887498949f   // 1/sqrt(80)
#define LOG2E  1.4426950408889634f

typedef __attribute__((ext_vector_type(8))) short          bf16x8;
typedef __attribute__((ext_vector_type(4))) float          f32x4;
typedef __attribute__((ext_vector_type(8))) unsigned short u16x8;
typedef __attribute__((ext_vector_type(4))) unsigned short u16x4;

__device__ __forceinline__ unsigned short f2bf(float x) {
    unsigned u = __float_as_uint(x);
    u += 0x7fffu + ((u >> 16) & 1u);
    return (unsigned short)(u >> 16);
}
__device__ __forceinline__ float bf2f(unsigned short h) {
    return __uint_as_float((unsigned)h << 16);
}
__device__ __forceinline__ f32x4 mfma16(bf16x8 a, bf16x8 b, f32x4 c) {
    return __builtin_amdgcn_mfma_f32_16x16x32_bf16(a, b, c, 0, 0, 0);
}
__device__ __forceinline__ float fexp2(float x) {
    return __builtin_amdgcn_exp2f(x);
}
__device__ __forceinline__ float max3f(float a, float b, float c) {
    return fmaxf(fmaxf(a, b), c);   // clang fuses to v_max3_f32
}
// async global->LDS DMA, 16B/lane, dest = lds base + lane*16
__device__ __forceinline__ void dma16(const void* g, void* s) {
    __builtin_amdgcn_global_load_lds(
        (const __attribute__((address_space(1))) void*)g,
        (__attribute__((address_space(3))) void*)s, 16, 0, 0);
}

// ---------------------------------------------------------------------------
// Convert fp32 -> bf16 (single, round-to-nearest). z: 0=X, 1=Wq(*SCALE*LOG2E),
// 2=Wk, 3=Wv, 4=Wo. grid=(1080,5), block 256, 16 elems/thread.
// ---------------------------------------------------------------------------
__global__ __launch_bounds__(256) void split_kernel(
    const float* __restrict__ X,  const float* __restrict__ Wq,
    const float* __restrict__ Wk, const float* __restrict__ Wv,
    const float* __restrict__ Wo,
    unsigned short* __restrict__ Xh,  unsigned short* __restrict__ Wqh,
    unsigned short* __restrict__ Wkh, unsigned short* __restrict__ Wvh,
    unsigned short* __restrict__ Woh)
{
    const int z = blockIdx.y;
    const float* src; unsigned short* dh; int n; float s = 1.0f;
    switch (z) {
        case 0:  src = X;  dh = Xh;  n = M_TOT * DIM; break;
        case 1:  src = Wq; dh = Wqh; n = DIM * DIM; s = SCALE * LOG2E; break;
        case 2:  src = Wk; dh = Wkh; n = DIM * DIM; break;
        case 3:  src = Wv; dh = Wvh; n = DIM * DIM; break;
        default: src = Wo; dh = Woh; n = DIM * DIM; break;
    }
    const int base = blockIdx.x * 4096 + threadIdx.x * 16;
    if (base >= n) return;
#pragma unroll
    for (int half = 0; half < 2; ++half) {
        const int b = base + half * 8;
        float4 a4 = *(const float4*)(src + b);
        float4 b4 = *(const float4*)(src + b + 4);
        float vv[8] = {a4.x, a4.y, a4.z, a4.w, b4.x, b4.y, b4.z, b4.w};
        union { unsigned short u[8]; u16x8 v; } ph;
#pragma unroll
        for (int j = 0; j < 8; ++j) ph.u[j] = f2bf(vv[j] * s);
        *(u16x8*)(dh + b) = ph.v;
    }
}

// ---------------------------------------------------------------------------
// QKV GEMM (single bf16). Tile 256(M) x 64(N), BK=32, block 256.
// Staging via global_load_lds (16B/lane), unpadded [r][32] LDS.
// grid=(27,10,3); z epilogue: 0 -> Qh bf16, 1 -> Kb bf16, 2 -> Vt transpose.
// ROUND-11: bijective XCD swizzle (m204 variant) -> A re-reads are L2 hits.
// ROUND-12: 2-phase double-buffered prefetch (one barrier/iter drain).
// ---------------------------------------------------------------------------
__global__ __launch_bounds__(256) void qkv_mfma_kernel(
    const unsigned short* __restrict__ Xh,
    const unsigned short* __restrict__ Wqh, const unsigned short* __restrict__ Wkh,
    const unsigned short* __restrict__ Wvh,
    unsigned short* __restrict__ Qh,
    unsigned short* __restrict__ Kb, unsigned short* __restrict__ VtG)
{
    __shared__ unsigned short smem[2][10240];   // 40 KB, double-buffered

    // ---- XCD-aware bijective remap: 810 blocks = 8*101 + 2 ----
    const int flat = blockIdx.x + 27 * (blockIdx.y + 10 * blockIdx.z);
    const int xcd  = flat & 7;
    const int slot = flat >> 3;                      // 0..101
    const int l    = (xcd < 2 ? xcd * 102 : 204 + (xcd - 2) * 101) + slot;
    const int m_idx = l / 30;                        // 0..26 (m-major: 30 tiles/panel)
    const int rem   = l - m_idx * 30;
    const int z     = rem / 10;                      // 0..2
    const int n_idx = rem - z * 10;                  // 0..9

    const unsigned short* WH = (z == 0) ? Wqh : ((z == 1) ? Wkh : Wvh);
    const int m0 = m_idx * 256;
    const int n0 = n_idx * 64;

    const int t    = threadIdx.x;
    const int w    = t >> 6;
    const int lane = t & 63;
    const int quad = lane >> 4;
    const int ln   = lane & 15;

    f32x4 acc[4][4];
#pragma unroll
    for (int mi = 0; mi < 4; ++mi)
#pragma unroll
        for (int nt = 0; nt < 4; ++nt)
#pragma unroll
            for (int e = 0; e < 4; ++e) acc[mi][nt][e] = 0.f;

    const int lr = lane >> 2;          // 0..15 (row within 16-row DMA chunk)
    const int lc = (lane & 3) * 8;     // 0,8,16,24 (shorts)

    // stage K-tile k0 into buffer buf (5 x 1KB DMA per wave)
    auto stage = [&](int buf, int k0) {
        unsigned short* As = smem[buf];
        unsigned short* Bs = smem[buf] + 8192;
        const unsigned short* gp = Xh + (size_t)(m0 + w * 64 + lr) * DIM + k0 + lc;
#pragma unroll
        for (int i = 0; i < 4; ++i)
            dma16(gp + (size_t)i * 16 * DIM, &As[(w * 64 + i * 16) * 32]);
        const size_t gb = (size_t)(n0 + w * 16 + lr) * DIM + k0 + lc;
        dma16(WH + gb, &Bs[w * 16 * 32]);
    };

    stage(0, 0);
    __syncthreads();                       // drains vmcnt(0): buf0 ready

    for (int k0 = 0; k0 < DIM; k0 += 32) {
        const int kb = (k0 >> 5) & 1;
        if (k0 + 32 < DIM) stage(kb ^ 1, k0 + 32);   // prefetch next tile

        const unsigned short* As = smem[kb];
        const unsigned short* Bs = smem[kb] + 8192;
        bf16x8 af[4];
#pragma unroll
        for (int mi = 0; mi < 4; ++mi)
            af[mi] = *(const bf16x8*)&As[(w * 64 + mi * 16 + ln) * 32 + quad * 8];
#pragma unroll
        for (int nt = 0; nt < 4; ++nt) {
            bf16x8 bh = *(const bf16x8*)&Bs[(nt * 16 + ln) * 32 + quad * 8];
#pragma unroll
            for (int mi = 0; mi < 4; ++mi)
                acc[mi][nt] = mfma16(af[mi], bh, acc[mi][nt]);
        }
        __syncthreads();   // vmcnt(0): prefetch landed; reads of kb done
    }

    if (z == 0) {
#pragma unroll
        for (int mi = 0; mi < 4; ++mi)
#pragma unroll
            for (int r = 0; r < 4; ++r) {
                const size_t row = m0 + w * 64 + mi * 16 + quad * 4 + r;
#pragma unroll
                for (int nt = 0; nt < 4; ++nt)
                    Qh[row * DIM + n0 + nt * 16 + ln] = f2bf(acc[mi][nt][r]);
            }
    } else if (z == 1) {
#pragma unroll
        for (int mi = 0; mi < 4; ++mi)
#pragma unroll
            for (int r = 0; r < 4; ++r) {
                const size_t row = m0 + w * 64 + mi * 16 + quad * 4 + r;
#pragma unroll
                for (int nt = 0; nt < 4; ++nt)
                    Kb[row * DIM + n0 + nt * 16 + ln] = f2bf(acc[mi][nt][r]);
            }
    } else {
        // transpose 256x64 -> Vt[64 n][256 m] in two 128-col halves via LDS
        unsigned short* Vts = smem[0];   // 64 x 136 = 8704 shorts
#pragma unroll 1
        for (int half = 0; half < 2; ++half) {
            __syncthreads();
            if ((w >> 1) == half) {
                const int wl = w & 1;
#pragma unroll
                for (int mi = 0; mi < 4; ++mi)
#pragma unroll
                    for (int nt = 0; nt < 4; ++nt)
#pragma unroll
                        for (int r = 0; r < 4; ++r)
                            Vts[(nt * 16 + ln) * 136 + wl * 64 + mi * 16 + quad * 4 + r] =
                                f2bf(acc[mi][nt][r]);
            }
            __syncthreads();
            const int nn = t & 63;
            const int c0 = (t >> 6) * 32;
#pragma unroll
            for (int i = 0; i < 4; ++i)
                *(u16x8*)(VtG + (size_t)(n0 + nn) * M_TOT + m0 + half * 128 + c0 + i * 8) =
                    *(const u16x8*)&Vts[nn * 136 + c0 + i * 8];
        }
    }
}

// ---------------------------------------------------------------------------
// Flash attention v15 (round-19). grid=(3,8,20), block 256 (4 waves x 48
// q-rows). 2x18 cross split (3-way split regressed twice — per-block
// overhead dominates; do NOT retry).
// Inner loop: P never touches LDS (sigma-permuted K staging); O^T PV;
// per-lane rescale/epilogue; defer-max; zero bank conflicts; K dbuf via
// DMA; V dbuf via reg-stage.
// ROUND-19: l computed INSIDE the PV MFMA via a 6th V^T row-group
// (rows 80..95: row 80 = bf16 ones, 81..95 zeros, initialized once).
// O^T[80][q] = sum_k P[k][q] = l: summed over all 64 keys by the MFMA
// K-reduction (no quad partials, no epilogue reduce), rescaled by aq
// automatically in the oacc rescale loop (was l_*=aq), and numerically
// consistent with the numerator (both sum bf16-truncated P). Deletes
// ~48 VALU adds + bookkeeping per wave-iter from the serial chain at
// the cost of +6 MFMA and +2 ds_reads. LDS 45 -> 49 KB (3 blocks/CU ok).
// NOTE: never leave MFMA-read LDS uninitialized — 0*NaN = NaN (round-7
// bug) — rows 81..95 are explicitly zeroed.
// NOTE: 128-thread blocks double FETCH + VGPR (round-9 regression).
// NOTE: no launch_bounds waves-cap / register-retained P across fences
// (round-15 spill).
// z<16: cross chunk -> partials (Pn,ml); z>=16: self frame -> Oh.
// ---------------------------------------------------------------------------
__global__ __launch_bounds__(256, 2) void attn_mfma_kernel(
    const unsigned short* __restrict__ Qh,
    const unsigned short* __restrict__ Kb, const unsigned short* __restrict__ Vt,
    unsigned short* __restrict__ Oh,
    unsigned short* __restrict__ Pn, float2* __restrict__ ml)
{
    // ---- XCD-aware remap: one head per XCD (480 = 8*60, bijective) ----
    const int flat = blockIdx.x + 3 * (blockIdx.y + 8 * blockIdx.z);
    const int h    = flat & 7;          // head = XCD
    const int slot = flat >> 3;         // 0..59
    const int z    = slot / 3;          // 0..19
    const int qt   = slot - z * 3;      // 0..2

    int f, kbase, nkt, idx = -1;
    if (z < 16) {
        idx = z;
        const int fi = z >> 1;
        f = 4 + fi;
        kbase = ((fi < 4 ? 4 : 8) + (z & 1) * 2) * SEQ;
        nkt = 18;
    } else {
        f = z - 16;
        kbase = f * SEQ;
        nkt = 9;
    }

    const int t    = threadIdx.x;
    const int w    = t >> 6;
    const int lane = t & 63;
    const int quad = lane >> 4;
    const int ln   = lane & 15;

    __shared__ unsigned short KhS[2][12 * 64 * 8]; // 24,576 B, sigma-permuted
    __shared__ unsigned short VtS[2][96 * 64];     // 24,576 B: 80 V rows + ones/zero group

    // sigma^-1: staging lane -> physical key offset within the 64-key tile
    const int klane = (lane & 3) | (((lane >> 4) & 1) << 2) |
                      (((lane >> 2) & 3) << 3) | (lane & 32);

    // staging helpers -------------------------------------------------------
    auto stage_k = [&](int buf, int kvt) {
        const unsigned short* kg = Kb + (size_t)(kbase + kvt * 64) * DIM + h * HD;
#pragma unroll
        for (int rnd = 0; rnd < 3; ++rnd) {
            const int g = rnd * 4 + w;          // d-colgroup 0..11
            dma16(kg + (size_t)klane * DIM + g * 8, &KhS[buf][g * 512]);
        }
    };
    u16x8 vreg[3];
    auto load_v = [&](int kvt) {
#pragma unroll
        for (int i = 0; i < 3; ++i) {
            const int u = t + i * 256;
            if (u < 640) {
                const int d = u >> 3, c8 = u & 7;
                vreg[i] = *(const u16x8*)(Vt + (size_t)(h * HD + d) * M_TOT +
                                          kbase + kvt * 64 + c8 * 8);
            }
        }
    };
    auto write_v = [&](int buf) {
#pragma unroll
        for (int i = 0; i < 3; ++i) {
            const int u = t + i * 256;
            if (u < 640) {
                const int d = u >> 3, c8 = u & 7;
                const int c8s = (c8 + 3 * d) & 7;
                *(u16x8*)&VtS[buf][d * 64 + c8s * 8] = vreg[i];
            }
        }
    };

    // ---- prologue part 1: issue tile-0 staging FIRST (latency in flight) ----
    stage_k(0, 0);
    load_v(0);

    // ---- ones/zero rows 80..95 of both V buffers (once; swizzle-invariant:
    //      each row is constant-valued). 2 bufs x 16 rows x 64 cols / 8 = 256
    //      u16x8 chunks = one per thread. ----
    {
        const int buf = t >> 7;                  // 0..1
        const int c   = t & 127;                 // chunk within buffer
        const int row = 80 + (c >> 3);
        const unsigned short val = (row == 80) ? (unsigned short)0x3F80 : (unsigned short)0;
        union { unsigned short u[8]; u16x8 v; } fill;
#pragma unroll
        for (int j = 0; j < 8; ++j) fill.u[j] = val;
        *(u16x8*)&VtS[buf][row * 64 + (c & 7) * 8] = fill.v;
    }

    // ---- Q fragments (B-operand of S^T) — overlap with staging latency ----
    bf16x8 qf[3][3];
#pragma unroll
    for (int mi = 0; mi < 3; ++mi) {
        const int qrow = f * SEQ + qt * 192 + w * 48 + mi * 16 + ln;
        const unsigned short* qp = Qh + (size_t)qrow * DIM + h * HD;
#pragma unroll
        for (int kc = 0; kc < 3; ++kc) {
            const int dbase = kc * 32 + quad * 8;
            if (dbase < HD) {
                qf[mi][kc] = *(const bf16x8*)(qp + dbase);
            } else {
                union { unsigned short u[8]; bf16x8 v; } zz;
#pragma unroll
                for (int j = 0; j < 8; ++j) zz.u[j] = 0;
                qf[mi][kc] = zz.v;
            }
        }
    }

    // per-lane running max for q = mi*16 + ln (replicated across quads)
    float m_[3];
#pragma unroll
    for (int mi = 0; mi < 3; ++mi) m_[mi] = -INFINITY;

    // oacc is O^T: lane(ln,quad) reg r holds O[q=mi*16+ln][d=nt*16+quad*4+r];
    // nt=5 is the l-row group (meaningful value at quad==0, r==0).
    f32x4 oacc[3][6];
#pragma unroll
    for (int mi = 0; mi < 3; ++mi)
#pragma unroll
        for (int nt = 0; nt < 6; ++nt)
#pragma unroll
            for (int e = 0; e < 4; ++e) oacc[mi][nt][e] = 0.f;

    // ---- prologue part 2: land V, then barrier ----
    write_v(0);          // compiler waits vmcnt for vreg before ds_write
    __syncthreads();     // vmcnt(0): K-DMA landed; lgkm(0): V + fill visible

    for (int kt = 0; kt < nkt; ++kt) {
        const int cur = kt & 1;
        const bool pf = (kt + 1 < nkt);

        // ---- prefetch next tile: issue loads, keep in flight ----
        if (pf) {
            load_v(kt + 1);            // global->reg, vmcnt in flight
            stage_k(cur ^ 1, kt + 1);  // global->LDS DMA, vmcnt in flight
        }

        // ---- S^T = K.Q^T (zero-C first MFMA; sigma-permuted key rows) ----
        const f32x4 fz = {0.f, 0.f, 0.f, 0.f};
        f32x4 sacc[3][4];
#pragma unroll
        for (int nt = 0; nt < 4; ++nt) {
            const int ks = ln + 16 * (nt >> 1) + 32 * (nt & 1);
#pragma unroll
            for (int kc = 0; kc < 3; ++kc) {
                bf16x8 kf = *(const bf16x8*)&KhS[cur][((kc * 4 + quad) * 64 + ks) * 8];
#pragma unroll
                for (int mi = 0; mi < 3; ++mi)
                    sacc[mi][nt] = (kc == 0)
                        ? mfma16(kf, qf[mi][0], fz)
                        : mfma16(kf, qf[mi][kc], sacc[mi][nt]);  // swapped!
            }
        }

        // ---- softmax: max3 trees, defer-max (l handled by PV's l-row) ----
        float mxl[3];
#pragma unroll
        for (int mi = 0; mi < 3; ++mi) {
            const f32x4* S = sacc[mi];
            const float a = max3f(S[0][0], S[0][1], S[0][2]);
            const float b = max3f(S[0][3], S[1][0], S[1][1]);
            const float c = max3f(S[1][2], S[1][3], S[2][0]);
            const float d = max3f(S[2][1], S[2][2], S[2][3]);
            const float e = max3f(S[3][0], S[3][1], S[3][2]);
            mxl[mi] = fmaxf(max3f(a, b, c), max3f(d, e, S[3][3]));
        }
        const bool need = (mxl[0] > m_[0] + 8.0f) || (mxl[1] > m_[1] + 8.0f) ||
                          (mxl[2] > m_[2] + 8.0f);
        if (__any(need)) {           // wave-uniform slow path (rare)
#pragma unroll
            for (int mi = 0; mi < 3; ++mi) {
                float mx = fmaxf(mxl[mi], __shfl_xor(mxl[mi], 16));
                mx = fmaxf(mx, __shfl_xor(mx, 32));
                const float mnew = fmaxf(m_[mi], mx);
                const float aq = fexp2(m_[mi] - mnew);
                m_[mi] = mnew;
                // O^T layout: q = ln per-lane -> rescale needs NO shuffles;
                // nt=5 (l-row) rescaled too == old l_*=aq.
#pragma unroll
                for (int nt = 0; nt < 6; ++nt)
#pragma unroll
                    for (int e = 0; e < 4; ++e) oacc[mi][nt][e] *= aq;
            }
        }
        // ---- exp + pack straight into PV B-frags (NO LDS round-trip) ----
        bf16x8 pfv[3][2];
#pragma unroll
        for (int mi = 0; mi < 3; ++mi) {
            float p[4][4];
#pragma unroll
            for (int nt = 0; nt < 4; ++nt) {
#pragma unroll
                for (int r = 0; r < 4; ++r)
                    p[nt][r] = fexp2(sacc[mi][nt][r] - m_[mi]);
            }
            union { unsigned w[4]; bf16x8 v; } u0, u1;
            u0.w[0] = __builtin_amdgcn_perm(__float_as_uint(p[0][1]),
                                            __float_as_uint(p[0][0]), 0x07060302u);
            u0.w[1] = __builtin_amdgcn_perm(__float_as_uint(p[0][3]),
                                            __float_as_uint(p[0][2]), 0x07060302u);
            u0.w[2] = __builtin_amdgcn_perm(__float_as_uint(p[2][1]),
                                            __float_as_uint(p[2][0]), 0x07060302u);
            u0.w[3] = __builtin_amdgcn_perm(__float_as_uint(p[2][3]),
                                            __float_as_uint(p[2][2]), 0x07060302u);
            u1.w[0] = __builtin_amdgcn_perm(__float_as_uint(p[1][1]),
                                            __float_as_uint(p[1][0]), 0x07060302u);
            u1.w[1] = __builtin_amdgcn_perm(__float_as_uint(p[1][3]),
                                            __float_as_uint(p[1][2]), 0x07060302u);
            u1.w[2] = __builtin_amdgcn_perm(__float_as_uint(p[3][1]),
                                            __float_as_uint(p[3][0]), 0x07060302u);
            u1.w[3] = __builtin_amdgcn_perm(__float_as_uint(p[3][3]),
                                            __float_as_uint(p[3][2]), 0x07060302u);
            pfv[mi][0] = u0.v;
            pfv[mi][1] = u1.v;
        }

        // ---- O^T += V^T.P : A = V^T from VtS (incl. l-row nt=5), B = pfv ----
#pragma unroll
        for (int kc = 0; kc < 2; ++kc)
#pragma unroll
            for (int nt = 0; nt < 6; ++nt) {
                const int vrow = nt * 16 + ln;
                const int c8r  = ((kc * 4 + quad) + 3 * vrow) & 7;
                bf16x8 vf = *(const bf16x8*)&VtS[cur][vrow * 64 + c8r * 8];
#pragma unroll
                for (int mi = 0; mi < 3; ++mi)
                    oacc[mi][nt] = mfma16(vf, pfv[mi][kc], oacc[mi][nt]);
            }

        // ---- land prefetched V into the other buffer, then barrier ----
        if (pf) write_v(cur ^ 1);
        __syncthreads();   // vmcnt(0): next K-DMA landed; all reads of cur done
    }

    // ---- epilogue: l lives in oacc[mi][5][0] at quad==0 (lanes 0..15);
    //      broadcast to all quads with one shuffle per mi. ----
#pragma unroll
    for (int mi = 0; mi < 3; ++mi) {
        const float lsum = __shfl(oacc[mi][5][0], ln, 64);
        const float inv = 1.f / lsum;
        const int rr = qt * 192 + w * 48 + mi * 16 + ln;    // frame-local q-row
#pragma unroll
        for (int nt = 0; nt < 5; ++nt) {
            union { unsigned short u[4]; u16x4 v; } o4;
#pragma unroll
            for (int r = 0; r < 4; ++r) o4.u[r] = f2bf(oacc[mi][nt][r] * inv);
            const int dcol = h * HD + nt * 16 + quad * 4;
            if (idx < 0)
                *(u16x4*)&Oh[((size_t)f * SEQ + rr) * DIM + dcol] = o4.v;
            else
                *(u16x4*)&Pn[((size_t)idx * SEQ + rr) * DIM + dcol] = o4.v;
        }
    }
    if (idx >= 0 && lane < 16) {
#pragma unroll
        for (int mi = 0; mi < 3; ++mi) {
            const int rr = qt * 192 + w * 48 + mi * 16 + lane;
            ml[((size_t)idx * 8 + h) * SEQ + rr] =
                make_float2(m_[mi], oacc[mi][5][0]);   // lane<16 == quad 0
        }
    }
}

// ---------------------------------------------------------------------------
// Merge the two partials of each cross frame. grid=(576,8), block 320.
// ---------------------------------------------------------------------------
__global__ __launch_bounds__(320) void merge_kernel(
    const unsigned short* __restrict__ Pn, const float2* __restrict__ ml,
    unsigned short* __restrict__ Oh)
{
    const int row = blockIdx.x;   // 0..575
    const int fi  = blockIdx.y;   // 0..7
    const int t   = threadIdx.x;  // 0..319
    const int i0  = fi * 2, i1 = i0 + 1;
#pragma unroll
    for (int rep = 0; rep < 2; ++rep) {
        const int col = t + rep * 320;
        const int h = col / 80;
        const float2 a = ml[((size_t)i0 * 8 + h) * SEQ + row];
        const float2 b = ml[((size_t)i1 * 8 + h) * SEQ + row];
        const float M  = fmaxf(a.x, b.x);
        const float w0 = fexp2(a.x - M) * a.y;
        const float w1 = fexp2(b.x - M) * b.y;
        const float inv = 1.f / (w0 + w1);
        const float p0 = bf2f(Pn[((size_t)i0 * SEQ + row) * DIM + col]);
        const float p1 = bf2f(Pn[((size_t)i1 * SEQ + row) * DIM + col]);
        Oh[((size_t)(4 + fi) * SEQ + row) * DIM + col] = f2bf((w0 * p0 + w1 * p1) * inv);
    }
}

// ---------------------------------------------------------------------------
// Output projection: out = Oh * Wo^T + bo (single bf16), fp32 out.
// Tile 256x64, BK=32, global_load_lds staging. grid=(27,10).
// ROUND-11: bijective XCD swizzle. ROUND-12: 2-phase dbuf prefetch.
// ---------------------------------------------------------------------------
__global__ __launch_bounds__(256) void oproj_mfma_kernel(
    const unsigned short* __restrict__ Oh,
    const unsigned short* __restrict__ Woh,
    const float* __restrict__ bo, float* __restrict__ out)
{
    __shared__ unsigned short smem[2][10240];

    // ---- XCD-aware bijective remap: 270 blocks = 8*33 + 6 ----
    const int flat = blockIdx.x + 27 * blockIdx.y;
    const int xcd  = flat & 7;
    const int slot = flat >> 3;
    const int l    = (xcd < 6 ? xcd * 34 : 204 + (xcd - 6) * 33) + slot;
    const int m_idx = l / 10;                        // m-major
    const int n_idx = l - m_idx * 10;
    const int m0 = m_idx * 256;
    const int n0 = n_idx * 64;

    const int t    = threadIdx.x;
    const int w    = t >> 6;
    const int lane = t & 63;
    const int quad = lane >> 4;
    const int ln   = lane & 15;

    f32x4 acc[4][4];
#pragma unroll
    for (int mi = 0; mi < 4; ++mi)
#pragma unroll
        for (int nt = 0; nt < 4; ++nt)
#pragma unroll
            for (int e = 0; e < 4; ++e) acc[mi][nt][e] = 0.f;

    const int lr = lane >> 2;
    const int lc = (lane & 3) * 8;

    auto stage = [&](int buf, int k0) {
        unsigned short* As = smem[buf];
        unsigned short* Bs = smem[buf] + 8192;
        const unsigned short* gp = Oh + (size_t)(m0 + w * 64 + lr) * DIM + k0 + lc;
#pragma unroll
        for (int i = 0; i < 4; ++i)
            dma16(gp + (size_t)i * 16 * DIM, &As[(w * 64 + i * 16) * 32]);
        const size_t gb = (size_t)(n0 + w * 16 + lr) * DIM + k0 + lc;
        dma16(Woh + gb, &Bs[w * 16 * 32]);
    };

    stage(0, 0);
    __syncthreads();

    for (int k0 = 0; k0 < DIM; k0 += 32) {
        const int kb = (k0 >> 5) & 1;
        if (k0 + 32 < DIM) stage(kb ^ 1, k0 + 32);

        const unsigned short* As = smem[kb];
        const unsigned short* Bs = smem[kb] + 8192;
        bf16x8 af[4];
#pragma unroll
        for (int mi = 0; mi < 4; ++mi)
            af[mi] = *(const bf16x8*)&As[(w * 64 + mi * 16 + ln) * 32 + quad * 8];
#pragma unroll
        for (int nt = 0; nt < 4; ++nt) {
            bf16x8 bh = *(const bf16x8*)&Bs[(nt * 16 + ln) * 32 + quad * 8];
#pragma unroll
            for (int mi = 0; mi < 4; ++mi)
                acc[mi][nt] = mfma16(af[mi], bh, acc[mi][nt]);
        }
        __syncthreads();
    }

#pragma unroll
    for (int mi = 0; mi < 4; ++mi)
#pragma unroll
        for (int r = 0; r < 4; ++r) {
            const size_t row = m0 + w * 64 + mi * 16 + quad * 4 + r;
#pragma unroll
            for (int nt = 0; nt < 4; ++nt) {
                const int col = n0 + nt * 16 + ln;
                out[row * DIM + col] = acc[mi][nt][r] + bo[col];
            }
        }
}

// ---------------------------------------------------------------------------
extern "C" void kernel_launch(void* const* d_in, const int* in_sizes, int n_in,
                              void* d_out, int out_size, void* d_ws, size_t ws_size,
                              hipStream_t stream)
{
    const float* x  = (const float*)d_in[0];
    const float* Wq = (const float*)d_in[1];
    const float* Wk = (const float*)d_in[2];
    const float* Wv = (const float*)d_in[3];
    const float* Wo = (const float*)d_in[4];
    const float* bo = (const float*)d_in[5];
    float* out = (float*)d_out;

    const size_t NX = (size_t)M_TOT * DIM;   // 4,423,680
    const size_t NW = (size_t)DIM * DIM;     // 409,600
    unsigned short* p = (unsigned short*)d_ws;
    unsigned short* Wqh = p;  p += NW;
    unsigned short* Wkh = p;  p += NW;
    unsigned short* Wvh = p;  p += NW;
    unsigned short* Woh = p;  p += NW;
    unsigned short* Xh  = p;  p += NX;
    unsigned short* Qhb = p;  p += NX;
    unsigned short* Kbb = p;  p += NX;
    unsigned short* Vtb = p;  p += NX;
    unsigned short* Ohb = Xh;                 // Xh dead after QKV GEMM

    // flash-decoding partials live in d_out (dead until oproj rewrites it)
    unsigned short* Pn = (unsigned short*)d_out;            // 16*576*640 bf16
    float2* ml = (float2*)((char*)d_out + (size_t)16 * SEQ * DIM * 2);

    dim3 g0((unsigned)((NX + 4095) / 4096), 5);
    split_kernel<<<g0, 256, 0, stream>>>(x, Wq, Wk, Wv, Wo,
        Xh, Wqh, Wkh, Wvh, Woh);

    dim3 g1(M_TOT / 256, DIM / 64, 3);
    qkv_mfma_kernel<<<g1, 256, 0, stream>>>(Xh, Wqh, Wkh, Wvh, Qhb, Kbb, Vtb);

    dim3 g2(3, HEADS, 20);
    attn_mfma_kernel<<<g2, 256, 0, stream>>>(Qhb, Kbb, Vtb, Ohb, Pn, ml);

    dim3 g3(SEQ, 8);
    merge_kernel<<<g3, 320, 0, stream>>>(Pn, ml, Ohb);

    dim3 g4(M_TOT / 256, DIM / 64);
    oproj_mfma_kernel<<<g4, 256, 0, stream>>>(Ohb, Woh, bo, out);
}

// Round 11
// 185.134 us; speedup vs baseline: 1.0736x; 1.0032x over previous
//
#include <hip/hip_runtime.h>
#include <hip/hip_bf16.h>

#define SEQ    576
#define DIM    640
#define HEADS  8
#define HD     80          // DIM / HEADS
#define NF     4
#define NB     12          // 3 * NF
#define M_TOT  (NB * SEQ)  // 6912
#define SCALE  0.11180339887498949f   // 1/sqrt(80)
#define LOG2E  1.4426950408889634f

typedef __attribute__((ext_vector_type(8))) short          bf16x8;
typedef __attribute__((ext_vector_type(4))) float          f32x4;
typedef __attribute__((ext_vector_type(8))) unsigned short u16x8;
typedef __attribute__((ext_vector_type(4))) unsigned short u16x4;

__device__ __forceinline__ unsigned short f2bf(float x) {
    unsigned u = __float_as_uint(x);
    u += 0x7fffu + ((u >> 16) & 1u);
    return (unsigned short)(u >> 16);
}
__device__ __forceinline__ float bf2f(unsigned short h) {
    return __uint_as_float((unsigned)h << 16);
}
__device__ __forceinline__ f32x4 mfma16(bf16x8 a, bf16x8 b, f32x4 c) {
    return __builtin_amdgcn_mfma_f32_16x16x32_bf16(a, b, c, 0, 0, 0);
}
__device__ __forceinline__ float fexp2(float x) {
    return __builtin_amdgcn_exp2f(x);
}
__device__ __forceinline__ float max3f(float a, float b, float c) {
    return fmaxf(fmaxf(a, b), c);   // clang fuses to v_max3_f32
}
// async global->LDS DMA, 16B/lane, dest = lds base + lane*16
__device__ __forceinline__ void dma16(const void* g, void* s) {
    __builtin_amdgcn_global_load_lds(
        (const __attribute__((address_space(1))) void*)g,
        (__attribute__((address_space(3))) void*)s, 16, 0, 0);
}

// ---------------------------------------------------------------------------
// Convert fp32 -> bf16 (single, round-to-nearest). z: 0=X, 1=Wq(*SCALE*LOG2E),
// 2=Wk, 3=Wv, 4=Wo. grid=(1080,5), block 256, 16 elems/thread.
// ---------------------------------------------------------------------------
__global__ __launch_bounds__(256) void split_kernel(
    const float* __restrict__ X,  const float* __restrict__ Wq,
    const float* __restrict__ Wk, const float* __restrict__ Wv,
    const float* __restrict__ Wo,
    unsigned short* __restrict__ Xh,  unsigned short* __restrict__ Wqh,
    unsigned short* __restrict__ Wkh, unsigned short* __restrict__ Wvh,
    unsigned short* __restrict__ Woh)
{
    const int z = blockIdx.y;
    const float* src; unsigned short* dh; int n; float s = 1.0f;
    switch (z) {
        case 0:  src = X;  dh = Xh;  n = M_TOT * DIM; break;
        case 1:  src = Wq; dh = Wqh; n = DIM * DIM; s = SCALE * LOG2E; break;
        case 2:  src = Wk; dh = Wkh; n = DIM * DIM; break;
        case 3:  src = Wv; dh = Wvh; n = DIM * DIM; break;
        default: src = Wo; dh = Woh; n = DIM * DIM; break;
    }
    const int base = blockIdx.x * 4096 + threadIdx.x * 16;
    if (base >= n) return;
#pragma unroll
    for (int half = 0; half < 2; ++half) {
        const int b = base + half * 8;
        float4 a4 = *(const float4*)(src + b);
        float4 b4 = *(const float4*)(src + b + 4);
        float vv[8] = {a4.x, a4.y, a4.z, a4.w, b4.x, b4.y, b4.z, b4.w};
        union { unsigned short u[8]; u16x8 v; } ph;
#pragma unroll
        for (int j = 0; j < 8; ++j) ph.u[j] = f2bf(vv[j] * s);
        *(u16x8*)(dh + b) = ph.v;
    }
}

// ---------------------------------------------------------------------------
// QKV GEMM (single bf16). ROUND-20/21: tile 128(M) x 64(N) (was 256x64),
// BK=32, block 256. Rationale: GEMMs are latency-bound (all pipes <31%);
// co-residency is the latency-hiding lever. 1620 blocks = 6.3/CU (was 3.2),
// LDS 24 KB -> 6 blocks/CU cap. Per-wave/K-step: 3 DMA + 6 ds_read + 8 MFMA.
// grid=(54,10,3); z epilogue: 0 -> Qh, 1 -> Kb, 2 -> Vt transpose.
// Bijective XCD swizzle (1620 = 8*202+4), m-major: per-XCD set =
// 6.75 A-panels (1.1 MB) + all weights (2.4 MB) ~ 3.6 MB, L2-fits.
// 2-phase double-buffered prefetch (one barrier/iter drain).
// (Round-21 = identical resubmit of round-20: bench infra failed, no data.)
// ---------------------------------------------------------------------------
__global__ __launch_bounds__(256) void qkv_mfma_kernel(
    const unsigned short* __restrict__ Xh,
    const unsigned short* __restrict__ Wqh, const unsigned short* __restrict__ Wkh,
    const unsigned short* __restrict__ Wvh,
    unsigned short* __restrict__ Qh,
    unsigned short* __restrict__ Kb, unsigned short* __restrict__ VtG)
{
    __shared__ unsigned short smem[2][6144];    // 24 KB: A 128x32 + B 64x32 per buf

    // ---- XCD-aware bijective remap: 1620 blocks = 8*202 + 4 ----
    const int flat = blockIdx.x + 54 * (blockIdx.y + 10 * blockIdx.z);
    const int xcd  = flat & 7;
    const int slot = flat >> 3;                      // 0..202
    const int l    = (xcd < 4 ? xcd * 203 : 812 + (xcd - 4) * 202) + slot;
    const int m_idx = l / 30;                        // 0..53 (m-major: 30 tiles/panel)
    const int rem   = l - m_idx * 30;
    const int z     = rem / 10;                      // 0..2
    const int n_idx = rem - z * 10;                  // 0..9

    const unsigned short* WH = (z == 0) ? Wqh : ((z == 1) ? Wkh : Wvh);
    const int m0 = m_idx * 128;
    const int n0 = n_idx * 64;

    const int t    = threadIdx.x;
    const int w    = t >> 6;
    const int lane = t & 63;
    const int quad = lane >> 4;
    const int ln   = lane & 15;

    f32x4 acc[2][4];
#pragma unroll
    for (int mi = 0; mi < 2; ++mi)
#pragma unroll
        for (int nt = 0; nt < 4; ++nt)
#pragma unroll
            for (int e = 0; e < 4; ++e) acc[mi][nt][e] = 0.f;

    const int lr = lane >> 2;          // 0..15 (row within 16-row DMA chunk)
    const int lc = (lane & 3) * 8;     // 0,8,16,24 (shorts)

    // stage K-tile k0 into buffer buf (3 x 1KB DMA per wave)
    auto stage = [&](int buf, int k0) {
        unsigned short* As = smem[buf];            // 128*32
        unsigned short* Bs = smem[buf] + 4096;     // 64*32
        const unsigned short* gp = Xh + (size_t)(m0 + w * 32 + lr) * DIM + k0 + lc;
#pragma unroll
        for (int i = 0; i < 2; ++i)
            dma16(gp + (size_t)i * 16 * DIM, &As[(w * 32 + i * 16) * 32]);
        const size_t gb = (size_t)(n0 + w * 16 + lr) * DIM + k0 + lc;
        dma16(WH + gb, &Bs[w * 16 * 32]);
    };

    stage(0, 0);
    __syncthreads();                       // drains vmcnt(0): buf0 ready

    for (int k0 = 0; k0 < DIM; k0 += 32) {
        const int kb = (k0 >> 5) & 1;
        if (k0 + 32 < DIM) stage(kb ^ 1, k0 + 32);   // prefetch next tile

        const unsigned short* As = smem[kb];
        const unsigned short* Bs = smem[kb] + 4096;
        bf16x8 af[2];
#pragma unroll
        for (int mi = 0; mi < 2; ++mi)
            af[mi] = *(const bf16x8*)&As[(w * 32 + mi * 16 + ln) * 32 + quad * 8];
#pragma unroll
        for (int nt = 0; nt < 4; ++nt) {
            bf16x8 bh = *(const bf16x8*)&Bs[(nt * 16 + ln) * 32 + quad * 8];
#pragma unroll
            for (int mi = 0; mi < 2; ++mi)
                acc[mi][nt] = mfma16(af[mi], bh, acc[mi][nt]);
        }
        __syncthreads();   // vmcnt(0): prefetch landed; reads of kb done
    }

    if (z == 0) {
#pragma unroll
        for (int mi = 0; mi < 2; ++mi)
#pragma unroll
            for (int r = 0; r < 4; ++r) {
                const size_t row = m0 + w * 32 + mi * 16 + quad * 4 + r;
#pragma unroll
                for (int nt = 0; nt < 4; ++nt)
                    Qh[row * DIM + n0 + nt * 16 + ln] = f2bf(acc[mi][nt][r]);
            }
    } else if (z == 1) {
#pragma unroll
        for (int mi = 0; mi < 2; ++mi)
#pragma unroll
            for (int r = 0; r < 4; ++r) {
                const size_t row = m0 + w * 32 + mi * 16 + quad * 4 + r;
#pragma unroll
                for (int nt = 0; nt < 4; ++nt)
                    Kb[row * DIM + n0 + nt * 16 + ln] = f2bf(acc[mi][nt][r]);
            }
    } else {
        // transpose 128x64 -> Vt[64 n][128 m] via LDS (single pass, 4 waves)
        unsigned short* Vts = smem[0];   // 64 x 136 = 8704 shorts <= 12288 avail
        // last loop iteration ended with __syncthreads(): smem reads done
#pragma unroll
        for (int mi = 0; mi < 2; ++mi)
#pragma unroll
            for (int nt = 0; nt < 4; ++nt)
#pragma unroll
                for (int r = 0; r < 4; ++r)
                    Vts[(nt * 16 + ln) * 136 + w * 32 + mi * 16 + quad * 4 + r] =
                        f2bf(acc[mi][nt][r]);
        __syncthreads();
        const int nn = t & 63;
        const int c0 = (t >> 6) * 32;
#pragma unroll
        for (int i = 0; i < 4; ++i)
            *(u16x8*)(VtG + (size_t)(n0 + nn) * M_TOT + m0 + c0 + i * 8) =
                *(const u16x8*)&Vts[nn * 136 + c0 + i * 8];
    }
}

// ---------------------------------------------------------------------------
// Flash attention v15 (round-19, UNCHANGED — structurally converged at
// ~56.4 us: all pipes <=29%, latency-bound intra-wave chain, block-split
// levers exhausted (3-way split regressed twice; per-block overhead ~37%)).
// grid=(3,8,20), block 256 (4 waves x 48 q-rows). 2x18 cross split.
// Inner loop: P never touches LDS (sigma-permuted K staging); O^T PV;
// per-lane rescale/epilogue; defer-max; zero bank conflicts; K dbuf via
// DMA; V dbuf via reg-stage; l computed INSIDE PV MFMA via ones-row 80.
// NOTE: never leave MFMA-read LDS uninitialized — 0*NaN = NaN.
// NOTE: 128-thread blocks double FETCH + VGPR. NOTE: no launch_bounds
// waves-cap / register-retained P across fences (round-15 spill).
// z<16: cross chunk -> partials (Pn,ml); z>=16: self frame -> Oh.
// ---------------------------------------------------------------------------
__global__ __launch_bounds__(256, 2) void attn_mfma_kernel(
    const unsigned short* __restrict__ Qh,
    const unsigned short* __restrict__ Kb, const unsigned short* __restrict__ Vt,
    unsigned short* __restrict__ Oh,
    unsigned short* __restrict__ Pn, float2* __restrict__ ml)
{
    // ---- XCD-aware remap: one head per XCD (480 = 8*60, bijective) ----
    const int flat = blockIdx.x + 3 * (blockIdx.y + 8 * blockIdx.z);
    const int h    = flat & 7;          // head = XCD
    const int slot = flat >> 3;         // 0..59
    const int z    = slot / 3;          // 0..19
    const int qt   = slot - z * 3;      // 0..2

    int f, kbase, nkt, idx = -1;
    if (z < 16) {
        idx = z;
        const int fi = z >> 1;
        f = 4 + fi;
        kbase = ((fi < 4 ? 4 : 8) + (z & 1) * 2) * SEQ;
        nkt = 18;
    } else {
        f = z - 16;
        kbase = f * SEQ;
        nkt = 9;
    }

    const int t    = threadIdx.x;
    const int w    = t >> 6;
    const int lane = t & 63;
    const int quad = lane >> 4;
    const int ln   = lane & 15;

    __shared__ unsigned short KhS[2][12 * 64 * 8]; // 24,576 B, sigma-permuted
    __shared__ unsigned short VtS[2][96 * 64];     // 24,576 B: 80 V rows + ones/zero group

    // sigma^-1: staging lane -> physical key offset within the 64-key tile
    const int klane = (lane & 3) | (((lane >> 4) & 1) << 2) |
                      (((lane >> 2) & 3) << 3) | (lane & 32);

    // staging helpers -------------------------------------------------------
    auto stage_k = [&](int buf, int kvt) {
        const unsigned short* kg = Kb + (size_t)(kbase + kvt * 64) * DIM + h * HD;
#pragma unroll
        for (int rnd = 0; rnd < 3; ++rnd) {
            const int g = rnd * 4 + w;          // d-colgroup 0..11
            dma16(kg + (size_t)klane * DIM + g * 8, &KhS[buf][g * 512]);
        }
    };
    u16x8 vreg[3];
    auto load_v = [&](int kvt) {
#pragma unroll
        for (int i = 0; i < 3; ++i) {
            const int u = t + i * 256;
            if (u < 640) {
                const int d = u >> 3, c8 = u & 7;
                vreg[i] = *(const u16x8*)(Vt + (size_t)(h * HD + d) * M_TOT +
                                          kbase + kvt * 64 + c8 * 8);
            }
        }
    };
    auto write_v = [&](int buf) {
#pragma unroll
        for (int i = 0; i < 3; ++i) {
            const int u = t + i * 256;
            if (u < 640) {
                const int d = u >> 3, c8 = u & 7;
                const int c8s = (c8 + 3 * d) & 7;
                *(u16x8*)&VtS[buf][d * 64 + c8s * 8] = vreg[i];
            }
        }
    };

    // ---- prologue part 1: issue tile-0 staging FIRST (latency in flight) ----
    stage_k(0, 0);
    load_v(0);

    // ---- ones/zero rows 80..95 of both V buffers (once; swizzle-invariant:
    //      each row is constant-valued). 2 bufs x 16 rows x 64 cols / 8 = 256
    //      u16x8 chunks = one per thread. ----
    {
        const int buf = t >> 7;                  // 0..1
        const int c   = t & 127;                 // chunk within buffer
        const int row = 80 + (c >> 3);
        const unsigned short val = (row == 80) ? (unsigned short)0x3F80 : (unsigned short)0;
        union { unsigned short u[8]; u16x8 v; } fill;
#pragma unroll
        for (int j = 0; j < 8; ++j) fill.u[j] = val;
        *(u16x8*)&VtS[buf][row * 64 + (c & 7) * 8] = fill.v;
    }

    // ---- Q fragments (B-operand of S^T) — overlap with staging latency ----
    bf16x8 qf[3][3];
#pragma unroll
    for (int mi = 0; mi < 3; ++mi) {
        const int qrow = f * SEQ + qt * 192 + w * 48 + mi * 16 + ln;
        const unsigned short* qp = Qh + (size_t)qrow * DIM + h * HD;
#pragma unroll
        for (int kc = 0; kc < 3; ++kc) {
            const int dbase = kc * 32 + quad * 8;
            if (dbase < HD) {
                qf[mi][kc] = *(const bf16x8*)(qp + dbase);
            } else {
                union { unsigned short u[8]; bf16x8 v; } zz;
#pragma unroll
                for (int j = 0; j < 8; ++j) zz.u[j] = 0;
                qf[mi][kc] = zz.v;
            }
        }
    }

    // per-lane running max for q = mi*16 + ln (replicated across quads)
    float m_[3];
#pragma unroll
    for (int mi = 0; mi < 3; ++mi) m_[mi] = -INFINITY;

    // oacc is O^T: lane(ln,quad) reg r holds O[q=mi*16+ln][d=nt*16+quad*4+r];
    // nt=5 is the l-row group (meaningful value at quad==0, r==0).
    f32x4 oacc[3][6];
#pragma unroll
    for (int mi = 0; mi < 3; ++mi)
#pragma unroll
        for (int nt = 0; nt < 6; ++nt)
#pragma unroll
            for (int e = 0; e < 4; ++e) oacc[mi][nt][e] = 0.f;

    // ---- prologue part 2: land V, then barrier ----
    write_v(0);          // compiler waits vmcnt for vreg before ds_write
    __syncthreads();     // vmcnt(0): K-DMA landed; lgkm(0): V + fill visible

    for (int kt = 0; kt < nkt; ++kt) {
        const int cur = kt & 1;
        const bool pf = (kt + 1 < nkt);

        // ---- prefetch next tile: issue loads, keep in flight ----
        if (pf) {
            load_v(kt + 1);            // global->reg, vmcnt in flight
            stage_k(cur ^ 1, kt + 1);  // global->LDS DMA, vmcnt in flight
        }

        // ---- S^T = K.Q^T (zero-C first MFMA; sigma-permuted key rows) ----
        const f32x4 fz = {0.f, 0.f, 0.f, 0.f};
        f32x4 sacc[3][4];
#pragma unroll
        for (int nt = 0; nt < 4; ++nt) {
            const int ks = ln + 16 * (nt >> 1) + 32 * (nt & 1);
#pragma unroll
            for (int kc = 0; kc < 3; ++kc) {
                bf16x8 kf = *(const bf16x8*)&KhS[cur][((kc * 4 + quad) * 64 + ks) * 8];
#pragma unroll
                for (int mi = 0; mi < 3; ++mi)
                    sacc[mi][nt] = (kc == 0)
                        ? mfma16(kf, qf[mi][0], fz)
                        : mfma16(kf, qf[mi][kc], sacc[mi][nt]);  // swapped!
            }
        }

        // ---- softmax: max3 trees, defer-max (l handled by PV's l-row) ----
        float mxl[3];
#pragma unroll
        for (int mi = 0; mi < 3; ++mi) {
            const f32x4* S = sacc[mi];
            const float a = max3f(S[0][0], S[0][1], S[0][2]);
            const float b = max3f(S[0][3], S[1][0], S[1][1]);
            const float c = max3f(S[1][2], S[1][3], S[2][0]);
            const float d = max3f(S[2][1], S[2][2], S[2][3]);
            const float e = max3f(S[3][0], S[3][1], S[3][2]);
            mxl[mi] = fmaxf(max3f(a, b, c), max3f(d, e, S[3][3]));
        }
        const bool need = (mxl[0] > m_[0] + 8.0f) || (mxl[1] > m_[1] + 8.0f) ||
                          (mxl[2] > m_[2] + 8.0f);
        if (__any(need)) {           // wave-uniform slow path (rare)
#pragma unroll
            for (int mi = 0; mi < 3; ++mi) {
                float mx = fmaxf(mxl[mi], __shfl_xor(mxl[mi], 16));
                mx = fmaxf(mx, __shfl_xor(mx, 32));
                const float mnew = fmaxf(m_[mi], mx);
                const float aq = fexp2(m_[mi] - mnew);
                m_[mi] = mnew;
                // O^T layout: q = ln per-lane -> rescale needs NO shuffles;
                // nt=5 (l-row) rescaled too == old l_*=aq.
#pragma unroll
                for (int nt = 0; nt < 6; ++nt)
#pragma unroll
                    for (int e = 0; e < 4; ++e) oacc[mi][nt][e] *= aq;
            }
        }
        // ---- exp + pack straight into PV B-frags (NO LDS round-trip) ----
        bf16x8 pfv[3][2];
#pragma unroll
        for (int mi = 0; mi < 3; ++mi) {
            float p[4][4];
#pragma unroll
            for (int nt = 0; nt < 4; ++nt) {
#pragma unroll
                for (int r = 0; r < 4; ++r)
                    p[nt][r] = fexp2(sacc[mi][nt][r] - m_[mi]);
            }
            union { unsigned w[4]; bf16x8 v; } u0, u1;
            u0.w[0] = __builtin_amdgcn_perm(__float_as_uint(p[0][1]),
                                            __float_as_uint(p[0][0]), 0x07060302u);
            u0.w[1] = __builtin_amdgcn_perm(__float_as_uint(p[0][3]),
                                            __float_as_uint(p[0][2]), 0x07060302u);
            u0.w[2] = __builtin_amdgcn_perm(__float_as_uint(p[2][1]),
                                            __float_as_uint(p[2][0]), 0x07060302u);
            u0.w[3] = __builtin_amdgcn_perm(__float_as_uint(p[2][3]),
                                            __float_as_uint(p[2][2]), 0x07060302u);
            u1.w[0] = __builtin_amdgcn_perm(__float_as_uint(p[1][1]),
                                            __float_as_uint(p[1][0]), 0x07060302u);
            u1.w[1] = __builtin_amdgcn_perm(__float_as_uint(p[1][3]),
                                            __float_as_uint(p[1][2]), 0x07060302u);
            u1.w[2] = __builtin_amdgcn_perm(__float_as_uint(p[3][1]),
                                            __float_as_uint(p[3][0]), 0x07060302u);
            u1.w[3] = __builtin_amdgcn_perm(__float_as_uint(p[3][3]),
                                            __float_as_uint(p[3][2]), 0x07060302u);
            pfv[mi][0] = u0.v;
            pfv[mi][1] = u1.v;
        }

        // ---- O^T += V^T.P : A = V^T from VtS (incl. l-row nt=5), B = pfv ----
#pragma unroll
        for (int kc = 0; kc < 2; ++kc)
#pragma unroll
            for (int nt = 0; nt < 6; ++nt) {
                const int vrow = nt * 16 + ln;
                const int c8r  = ((kc * 4 + quad) + 3 * vrow) & 7;
                bf16x8 vf = *(const bf16x8*)&VtS[cur][vrow * 64 + c8r * 8];
#pragma unroll
                for (int mi = 0; mi < 3; ++mi)
                    oacc[mi][nt] = mfma16(vf, pfv[mi][kc], oacc[mi][nt]);
            }

        // ---- land prefetched V into the other buffer, then barrier ----
        if (pf) write_v(cur ^ 1);
        __syncthreads();   // vmcnt(0): next K-DMA landed; all reads of cur done
    }

    // ---- epilogue: l lives in oacc[mi][5][0] at quad==0 (lanes 0..15);
    //      broadcast to all quads with one shuffle per mi. ----
#pragma unroll
    for (int mi = 0; mi < 3; ++mi) {
        const float lsum = __shfl(oacc[mi][5][0], ln, 64);
        const float inv = 1.f / lsum;
        const int rr = qt * 192 + w * 48 + mi * 16 + ln;    // frame-local q-row
#pragma unroll
        for (int nt = 0; nt < 5; ++nt) {
            union { unsigned short u[4]; u16x4 v; } o4;
#pragma unroll
            for (int r = 0; r < 4; ++r) o4.u[r] = f2bf(oacc[mi][nt][r] * inv);
            const int dcol = h * HD + nt * 16 + quad * 4;
            if (idx < 0)
                *(u16x4*)&Oh[((size_t)f * SEQ + rr) * DIM + dcol] = o4.v;
            else
                *(u16x4*)&Pn[((size_t)idx * SEQ + rr) * DIM + dcol] = o4.v;
        }
    }
    if (idx >= 0 && lane < 16) {
#pragma unroll
        for (int mi = 0; mi < 3; ++mi) {
            const int rr = qt * 192 + w * 48 + mi * 16 + lane;
            ml[((size_t)idx * 8 + h) * SEQ + rr] =
                make_float2(m_[mi], oacc[mi][5][0]);   // lane<16 == quad 0
        }
    }
}

// ---------------------------------------------------------------------------
// Merge the two partials of each cross frame. grid=(576,8), block 320.
// ---------------------------------------------------------------------------
__global__ __launch_bounds__(320) void merge_kernel(
    const unsigned short* __restrict__ Pn, const float2* __restrict__ ml,
    unsigned short* __restrict__ Oh)
{
    const int row = blockIdx.x;   // 0..575
    const int fi  = blockIdx.y;   // 0..7
    const int t   = threadIdx.x;  // 0..319
    const int i0  = fi * 2, i1 = i0 + 1;
#pragma unroll
    for (int rep = 0; rep < 2; ++rep) {
        const int col = t + rep * 320;
        const int h = col / 80;
        const float2 a = ml[((size_t)i0 * 8 + h) * SEQ + row];
        const float2 b = ml[((size_t)i1 * 8 + h) * SEQ + row];
        const float M  = fmaxf(a.x, b.x);
        const float w0 = fexp2(a.x - M) * a.y;
        const float w1 = fexp2(b.x - M) * b.y;
        const float inv = 1.f / (w0 + w1);
        const float p0 = bf2f(Pn[((size_t)i0 * SEQ + row) * DIM + col]);
        const float p1 = bf2f(Pn[((size_t)i1 * SEQ + row) * DIM + col]);
        Oh[((size_t)(4 + fi) * SEQ + row) * DIM + col] = f2bf((w0 * p0 + w1 * p1) * inv);
    }
}

// ---------------------------------------------------------------------------
// Output projection: out = Oh * Wo^T + bo (single bf16), fp32 out.
// ROUND-20/21: tile 128(M) x 64(N) (was 256x64) -> grid (54,10) = 540 blocks
// = 2.1/CU (was 1.05/CU: ZERO co-residency, nothing to hide the latency-
// bound staging chain — the worst-occupancy kernel in the pipeline).
// BK=32, global_load_lds staging, 2-phase dbuf prefetch, bijective XCD
// swizzle (540 = 8*67 + 4).
// ---------------------------------------------------------------------------
__global__ __launch_bounds__(256) void oproj_mfma_kernel(
    const unsigned short* __restrict__ Oh,
    const unsigned short* __restrict__ Woh,
    const float* __restrict__ bo, float* __restrict__ out)
{
    __shared__ unsigned short smem[2][6144];    // 24 KB

    // ---- XCD-aware bijective remap: 540 blocks = 8*67 + 4 ----
    const int flat = blockIdx.x + 54 * blockIdx.y;
    const int xcd  = flat & 7;
    const int slot = flat >> 3;
    const int l    = (xcd < 4 ? xcd * 68 : 272 + (xcd - 4) * 67) + slot;
    const int m_idx = l / 10;                        // 0..53 (m-major)
    const int n_idx = l - m_idx * 10;
    const int m0 = m_idx * 128;
    const int n0 = n_idx * 64;

    const int t    = threadIdx.x;
    const int w    = t >> 6;
    const int lane = t & 63;
    const int quad = lane >> 4;
    const int ln   = lane & 15;

    f32x4 acc[2][4];
#pragma unroll
    for (int mi = 0; mi < 2; ++mi)
#pragma unroll
        for (int nt = 0; nt < 4; ++nt)
#pragma unroll
            for (int e = 0; e < 4; ++e) acc[mi][nt][e] = 0.f;

    const int lr = lane >> 2;
    const int lc = (lane & 3) * 8;

    auto stage = [&](int buf, int k0) {
        unsigned short* As = smem[buf];            // 128*32
        unsigned short* Bs = smem[buf] + 4096;     // 64*32
        const unsigned short* gp = Oh + (size_t)(m0 + w * 32 + lr) * DIM + k0 + lc;
#pragma unroll
        for (int i = 0; i < 2; ++i)
            dma16(gp + (size_t)i * 16 * DIM, &As[(w * 32 + i * 16) * 32]);
        const size_t gb = (size_t)(n0 + w * 16 + lr) * DIM + k0 + lc;
        dma16(Woh + gb, &Bs[w * 16 * 32]);
    };

    stage(0, 0);
    __syncthreads();

    for (int k0 = 0; k0 < DIM; k0 += 32) {
        const int kb = (k0 >> 5) & 1;
        if (k0 + 32 < DIM) stage(kb ^ 1, k0 + 32);

        const unsigned short* As = smem[kb];
        const unsigned short* Bs = smem[kb] + 4096;
        bf16x8 af[2];
#pragma unroll
        for (int mi = 0; mi < 2; ++mi)
            af[mi] = *(const bf16x8*)&As[(w * 32 + mi * 16 + ln) * 32 + quad * 8];
#pragma unroll
        for (int nt = 0; nt < 4; ++nt) {
            bf16x8 bh = *(const bf16x8*)&Bs[(nt * 16 + ln) * 32 + quad * 8];
#pragma unroll
            for (int mi = 0; mi < 2; ++mi)
                acc[mi][nt] = mfma16(af[mi], bh, acc[mi][nt]);
        }
        __syncthreads();
    }

#pragma unroll
    for (int mi = 0; mi < 2; ++mi)
#pragma unroll
        for (int r = 0; r < 4; ++r) {
            const size_t row = m0 + w * 32 + mi * 16 + quad * 4 + r;
#pragma unroll
            for (int nt = 0; nt < 4; ++nt) {
                const int col = n0 + nt * 16 + ln;
                out[row * DIM + col] = acc[mi][nt][r] + bo[col];
            }
        }
}

// ---------------------------------------------------------------------------
extern "C" void kernel_launch(void* const* d_in, const int* in_sizes, int n_in,
                              void* d_out, int out_size, void* d_ws, size_t ws_size,
                              hipStream_t stream)
{
    const float* x  = (const float*)d_in[0];
    const float* Wq = (const float*)d_in[1];
    const float* Wk = (const float*)d_in[2];
    const float* Wv = (const float*)d_in[3];
    const float* Wo = (const float*)d_in[4];
    const float* bo = (const float*)d_in[5];
    float* out = (float*)d_out;

    const size_t NX = (size_t)M_TOT * DIM;   // 4,423,680
    const size_t NW = (size_t)DIM * DIM;     // 409,600
    unsigned short* p = (unsigned short*)d_ws;
    unsigned short* Wqh = p;  p += NW;
    unsigned short* Wkh = p;  p += NW;
    unsigned short* Wvh = p;  p += NW;
    unsigned short* Woh = p;  p += NW;
    unsigned short* Xh  = p;  p += NX;
    unsigned short* Qhb = p;  p += NX;
    unsigned short* Kbb = p;  p += NX;
    unsigned short* Vtb = p;  p += NX;
    unsigned short* Ohb = Xh;                 // Xh dead after QKV GEMM

    // flash-decoding partials live in d_out (dead until oproj rewrites it)
    unsigned short* Pn = (unsigned short*)d_out;            // 16*576*640 bf16
    float2* ml = (float2*)((char*)d_out + (size_t)16 * SEQ * DIM * 2);

    dim3 g0((unsigned)((NX + 4095) / 4096), 5);
    split_kernel<<<g0, 256, 0, stream>>>(x, Wq, Wk, Wv, Wo,
        Xh, Wqh, Wkh, Wvh, Woh);

    dim3 g1(M_TOT / 128, DIM / 64, 3);
    qkv_mfma_kernel<<<g1, 256, 0, stream>>>(Xh, Wqh, Wkh, Wvh, Qhb, Kbb, Vtb);

    dim3 g2(3, HEADS, 20);
    attn_mfma_kernel<<<g2, 256, 0, stream>>>(Qhb, Kbb, Vtb, Ohb, Pn, ml);

    dim3 g3(SEQ, 8);
    merge_kernel<<<g3, 320, 0, stream>>>(Pn, ml, Ohb);

    dim3 g4(M_TOT / 128, DIM / 64);
    oproj_mfma_kernel<<<g4, 256, 0, stream>>>(Ohb, Woh, bo, out);
}